// Round 8
// baseline (270.031 us; speedup 1.0000x reference)
//
#include <hip/hip_runtime.h>

// ---------------------------------------------------------------------------
// MultiHeadAttention, fp32 in/out. DIAGNOSTIC ROUND: qkv split into 2 mt-half
// launches (256 blocks each, arithmetic identical) so the top-5 rocprof slots
// reveal the true duration of attn_tscore / prep / merge / out_gemm2, which
// are currently all hidden below qkv's 77us x5 dispatches.
//   prep       : Wqkv^T/Wout^T transpose+split-bf16, x split-bf16 (fused)
//   qkv_gemm8  : 128x192 split-bf16 MFMA, 2-phase/K-tile, 2x40KB LDS
//   attn_tscore: transposed-score flash, KVBLK=64, KV-SPLIT x2
//   attn_merge : LSE-merge of 2 partials -> split-bf16 ctx
//   out_gemm2  : 128x64 split-bf16 MFMA, 2-phase, 2x24KB LDS
// ---------------------------------------------------------------------------

typedef __attribute__((ext_vector_type(8)))  short short8;
typedef __attribute__((ext_vector_type(4)))  short short4v;
typedef __attribute__((ext_vector_type(8)))  float float8;
typedef __attribute__((ext_vector_type(4)))  float f32x4;
typedef __attribute__((ext_vector_type(16))) float f32x16;
typedef __attribute__((ext_vector_type(4)))  int   int4v;

#define D_MODEL 1024
#define NHEAD   16
#define HD      64
#define SEQ     2048
#define N3      (3*D_MODEL)
#define MB      (1024*1024)

static __device__ __forceinline__ float bf2f(short s) {
    unsigned u = ((unsigned)(unsigned short)s) << 16;
    return __builtin_bit_cast(float, u);
}
static __device__ __forceinline__ short f2bf(float f) {
    unsigned u = __builtin_bit_cast(unsigned, f);
    u = (u + 0x7fff + ((u >> 16) & 1)) >> 16;   // RNE
    return (short)u;
}
// hardware packed f32->bf16 (RNE), 1 instr
static __device__ __forceinline__ unsigned cvtpk(float a, float b) {
    unsigned r;
    asm("v_cvt_pk_bf16_f32 %0, %1, %2" : "=v"(r) : "v"(a), "v"(b));
    return r;
}
// in-place cross-half swap: a[32..63] <-> b[0..31]
#define PLSWAP(a, b) asm("v_permlane32_swap_b32 %0, %1" : "+v"(a), "+v"(b))

static __device__ __forceinline__ void gl16(const short* g, short* l) {
    __builtin_amdgcn_global_load_lds(
        (const __attribute__((address_space(1))) unsigned int*)g,
        (__attribute__((address_space(3))) unsigned int*)l, 16, 0, 0);
}

// ---------------------------------------------------------------------------
// prep: blocks [0,2048) split x; [2048,5120) transpose-split Wqkv;
//       [5120,6144) transpose-split Wout.
// ---------------------------------------------------------------------------
__global__ __launch_bounds__(256) void prep(
    const float* __restrict__ x, const float* __restrict__ Wqkv,
    const float* __restrict__ Wout,
    short* __restrict__ Xh, short* __restrict__ Xl,
    short* __restrict__ Wh, short* __restrict__ Wl,
    short* __restrict__ Woh, short* __restrict__ Wol)
{
    __shared__ float tile[32][33];
    const int bid = blockIdx.x;
    const int tid = threadIdx.x;

    if (bid < 2048) {                        // ---- split x ----
        const int i = (bid * 256 + tid) * 8;
        const float8 v = *(const float8*)&x[i];
        short8 h, l;
#pragma unroll
        for (int j = 0; j < 8; ++j) {
            h[j] = f2bf(v[j]);
            l[j] = f2bf(v[j] - bf2f(h[j]));
        }
        *(short8*)&Xh[i] = h;
        *(short8*)&Xl[i] = l;
        return;
    }

    // ---- transpose + split a weight matrix ----
    const float* in; short *hi, *lo; int K, N, bx, by;
    if (bid < 5120) {
        const int b2 = bid - 2048;
        in = Wqkv; hi = Wh; lo = Wl; K = D_MODEL; N = N3;
        bx = b2 % 96; by = b2 / 96;
    } else {
        const int b3 = bid - 5120;
        in = Wout; hi = Woh; lo = Wol; K = D_MODEL; N = D_MODEL;
        bx = b3 & 31; by = b3 >> 5;
    }
    const int n0 = bx * 32, k0 = by * 32;
    const int tx = tid & 31, ty = tid >> 5;
#pragma unroll
    for (int i = 0; i < 4; ++i)
        tile[ty + 8*i][tx] = in[(k0 + ty + 8*i) * N + (n0 + tx)];
    __syncthreads();
#pragma unroll
    for (int i = 0; i < 4; ++i) {
        const float v  = tile[tx][ty + 8*i];
        const short vh = f2bf(v);
        const short vl = f2bf(v - bf2f(vh));
        const int idx  = (n0 + ty + 8*i) * K + (k0 + tx);
        hi[idx] = vh;
        lo[idx] = vl;
    }
}

// ---------------------------------------------------------------------------
// QKV GEMM (R5 structure). BM=128 BN=192 BK=32, 512 threads (8 waves 2Mx4N),
// per-wave output 64x48. LDS: 2 x 40KB buffers. DIAGNOSTIC: launched twice
// with mt0 = 0 / 16 (256 blocks each) to un-hide other kernels in top-5.
// ---------------------------------------------------------------------------
#define QBUF_SH 20480          // shorts per LDS buffer (40KB)
#define OFF_AL  4096
#define OFF_BH  8192
#define OFF_BL  14336

__global__ __launch_bounds__(512, 4) void qkv_gemm8(
    const short* __restrict__ Xh, const short* __restrict__ Xl,
    const short* __restrict__ Bh, const short* __restrict__ Bl,
    const float* __restrict__ bias,
    short* __restrict__ Qo, short* __restrict__ Ko, short* __restrict__ Vt,
    int mt0)
{
    __shared__ __attribute__((aligned(16))) short smem[2 * QBUF_SH];

    const int tid  = threadIdx.x;
    const int wave = tid >> 6, lane = tid & 63;
    const int q4 = lane >> 4, l16 = lane & 15;
    const int wr = wave >> 2, wc = wave & 3;
    const int csw = (q4 ^ ((l16 ^ (l16 >> 2)) & 3)) * 8;

    // 256-block XCD swizzle: 32 contiguous per XCD, mt fast within XCD
    const int flat = blockIdx.x;
    const int sw = (flat & 7) * 32 + (flat >> 3);
    const int mt = mt0 + (sw & 15), nt = sw >> 4;
    const int m0 = mt * 128, n0 = nt * 192;

    // staging map: 2560 chunks = [Ah 512][Al 512][Bh 768][Bl 768], 5/thread
    const short* srcp[5];
#pragma unroll
    for (int j = 0; j < 5; ++j) {
        const int id = j * 512 + tid;
        int r; const short* mat; int row0;
        if (id < 512)       { r = id >> 2;          mat = Xh; row0 = m0; }
        else if (id < 1024) { r = (id - 512) >> 2;  mat = Xl; row0 = m0; }
        else if (id < 1792) { r = (id - 1024) >> 2; mat = Bh; row0 = n0; }
        else                { r = (id - 1792) >> 2; mat = Bl; row0 = n0; }
        const int cg = (id & 3) ^ ((r ^ (r >> 2)) & 3);
        srcp[j] = &mat[(size_t)(row0 + r) * D_MODEL + cg * 8];
    }

    auto stage = [&](int b) {
#pragma unroll
        for (int j = 0; j < 5; ++j) {
            gl16(srcp[j], smem + b * QBUF_SH + (j * 512 + tid) * 8);
            srcp[j] += 32;                  // advance one K-tile
        }
    };

    f32x4 acc[4][3];
#pragma unroll
    for (int i = 0; i < 4; ++i)
#pragma unroll
        for (int j = 0; j < 3; ++j) acc[i][j] = (f32x4){0.f, 0.f, 0.f, 0.f};

    stage(0);
    asm volatile("s_waitcnt vmcnt(0)" ::: "memory");
    __builtin_amdgcn_s_barrier();

    for (int t = 0; t < 32; ++t) {
        const int cur = t & 1;
        const short* base = smem + cur * QBUF_SH;
        const short* Ah_s = base;
        const short* Al_s = base + OFF_AL;
        const short* Bh_s = base + OFF_BH;
        const short* Bl_s = base + OFF_BL;

        // ---- phase 0: B frags + A frags ti=0..1; prefetch next K-tile ----
        short8 bhf[3], blf[3], a0h[2], a0l[2];
#pragma unroll
        for (int n = 0; n < 3; ++n) {
            const int rb = (wc * 48 + n * 16 + l16) * 32 + csw;
            bhf[n] = *(const short8*)(Bh_s + rb);
            blf[n] = *(const short8*)(Bl_s + rb);
        }
#pragma unroll
        for (int ti = 0; ti < 2; ++ti) {
            const int ra = (wr * 64 + ti * 16 + l16) * 32 + csw;
            a0h[ti] = *(const short8*)(Ah_s + ra);
            a0l[ti] = *(const short8*)(Al_s + ra);
        }
        if (t < 31) stage(cur ^ 1);         // stays in flight across barriers
        __builtin_amdgcn_s_barrier();
        asm volatile("s_waitcnt lgkmcnt(0)" ::: "memory");
        __builtin_amdgcn_sched_barrier(0);
        // early-issue phase-1 A frags (complete under phase-0 MFMA)
        short8 a1h[2], a1l[2];
#pragma unroll
        for (int ti = 0; ti < 2; ++ti) {
            const int ra = (wr * 64 + (2 + ti) * 16 + l16) * 32 + csw;
            a1h[ti] = *(const short8*)(Ah_s + ra);
            a1l[ti] = *(const short8*)(Al_s + ra);
        }
        __builtin_amdgcn_sched_barrier(0);
        __builtin_amdgcn_s_setprio(1);
#pragma unroll
        for (int ti = 0; ti < 2; ++ti)
#pragma unroll
            for (int n = 0; n < 3; ++n) {
                acc[ti][n] = __builtin_amdgcn_mfma_f32_16x16x32_bf16(a0h[ti], bhf[n], acc[ti][n], 0, 0, 0);
                acc[ti][n] = __builtin_amdgcn_mfma_f32_16x16x32_bf16(a0h[ti], blf[n], acc[ti][n], 0, 0, 0);
                acc[ti][n] = __builtin_amdgcn_mfma_f32_16x16x32_bf16(a0l[ti], bhf[n], acc[ti][n], 0, 0, 0);
            }
        __builtin_amdgcn_s_setprio(0);
        __builtin_amdgcn_s_barrier();

        // ---- phase 1: A frags ti=2..3 (already in flight) ----
        asm volatile("s_waitcnt lgkmcnt(0)" ::: "memory");
        __builtin_amdgcn_sched_barrier(0);
        __builtin_amdgcn_s_setprio(1);
#pragma unroll
        for (int ti = 0; ti < 2; ++ti)
#pragma unroll
            for (int n = 0; n < 3; ++n) {
                acc[2+ti][n] = __builtin_amdgcn_mfma_f32_16x16x32_bf16(a1h[ti], bhf[n], acc[2+ti][n], 0, 0, 0);
                acc[2+ti][n] = __builtin_amdgcn_mfma_f32_16x16x32_bf16(a1h[ti], blf[n], acc[2+ti][n], 0, 0, 0);
                acc[2+ti][n] = __builtin_amdgcn_mfma_f32_16x16x32_bf16(a1l[ti], bhf[n], acc[2+ti][n], 0, 0, 0);
            }
        __builtin_amdgcn_s_setprio(0);
        asm volatile("s_waitcnt vmcnt(0)" ::: "memory");
        __builtin_amdgcn_s_barrier();
    }

    // epilogue: scatter Q (pre-scaled), K, Vt
    const float SCALE_Q = 0.125f * 1.4426950408889634f;
#pragma unroll
    for (int tj = 0; tj < 3; ++tj) {
        const int jj = wc * 48 + tj * 16 + l16;   // 0..191 within head
        const int n  = nt * 192 + jj;
        const float bv = bias[n];
#pragma unroll
        for (int ti = 0; ti < 4; ++ti) {
            const int mb = m0 + wr * 64 + ti * 16 + q4 * 4;
            const int b = mb >> 11;
            const int s = mb & 2047;
            const int bh_ = b * NHEAD + nt;
            if (jj >= 128) {                      // Vt: s is fast axis -> short4
                short4v v4;
#pragma unroll
                for (int r = 0; r < 4; ++r) v4[r] = f2bf(acc[ti][tj][r] + bv);
                *(short4v*)&Vt[(bh_ * HD + (jj - 128)) * SEQ + s] = v4;
            } else if (jj < 64) {
#pragma unroll
                for (int r = 0; r < 4; ++r)
                    Qo[(bh_ * SEQ + s + r) * HD + jj] = f2bf((acc[ti][tj][r] + bv) * SCALE_Q);
            } else {
#pragma unroll
                for (int r = 0; r < 4; ++r)
                    Ko[(bh_ * SEQ + s + r) * HD + (jj - 64)] = f2bf(acc[ti][tj][r] + bv);
            }
        }
    }
}

// ---------------------------------------------------------------------------
// Transposed-score flash attention, KV-SPLIT x2. Grid (32 bh, 16 qb, 2 kvz);
// each block does 1024 keys (16 iters of 64), double-buffered K/V LDS, async
// reg-staging, ONE barrier per iter. Writes UNNORMALIZED O partial (f32,
// MFMA register layout, coalesced) + per-row (m, l). 4 blocks/CU.
// ---------------------------------------------------------------------------
__global__ __launch_bounds__(256, 2) void attn_tscore(
    const short* __restrict__ Q, const short* __restrict__ K,
    const short* __restrict__ Vt,
    float* __restrict__ Opart, float2* __restrict__ Ml)
{
    __shared__ __attribute__((aligned(16))) char smem[36864];
    short (*Ks)[72] = (short(*)[72])smem;                 // [2*64 key][64 d + pad]
    short (*Vs)[72] = (short(*)[72])(smem + 18432);       // [2*64 d][64 key + pad]

    const int bh  = blockIdx.x;               // 0..31
    const int qb  = blockIdx.y;               // 0..15
    const int kvz = blockIdx.z;               // 0..1

    const short* Qp  = Q  + (size_t)bh * SEQ * HD;
    const short* Kp  = K  + (size_t)bh * SEQ * HD + (size_t)kvz * 1024 * HD;
    const short* Vtp = Vt + (size_t)bh * HD * SEQ + (size_t)kvz * 1024;

    const int tid  = threadIdx.x;
    const int wave = tid >> 6, lane = tid & 63;
    const int l5 = lane & 31, hf = lane >> 5;
    const int q0w = qb * 128 + wave * 32;

    short8 qf[4];
#pragma unroll
    for (int c = 0; c < 4; ++c)
        qf[c] = *(const short8*)&Qp[(q0w + l5) * HD + c * 16 + hf * 8];

    f32x16 oacc0 = (f32x16)(0.f), oacc1 = (f32x16)(0.f);
    float m = -1.0e30f, l = 0.f;

    // staging: 256 threads cover 64 rows x 64 cols (2x short8 each for K and V)
    const int sr = tid >> 2;          // 0..63
    const int sc = (tid & 3) * 16;    // 0,16,32,48

    short8 kr0 = *(const short8*)&Kp[sr * HD + sc];
    short8 kr1 = *(const short8*)&Kp[sr * HD + sc + 8];
    short8 vr0 = *(const short8*)&Vtp[sr * SEQ + sc];
    short8 vr1 = *(const short8*)&Vtp[sr * SEQ + sc + 8];
    *(short8*)&Ks[sr][sc]     = kr0;
    *(short8*)&Ks[sr][sc + 8] = kr1;
    *(short8*)&Vs[sr][sc]     = vr0;
    *(short8*)&Vs[sr][sc + 8] = vr1;
    __syncthreads();

    for (int kc = 0; kc < 16; ++kc) {
        const int buf = (kc & 1) << 6;

        // issue next tile's global loads (hidden under this tile's compute)
        if (kc < 15) {
            const int nkb = (kc + 1) << 6;
            kr0 = *(const short8*)&Kp[(nkb + sr) * HD + sc];
            kr1 = *(const short8*)&Kp[(nkb + sr) * HD + sc + 8];
            vr0 = *(const short8*)&Vtp[sr * SEQ + nkb + sc];
            vr1 = *(const short8*)&Vtp[sr * SEQ + nkb + sc + 8];
        }

        // ---- scores: two 32-key tiles ----
        f32x16 s0 = (f32x16)(0.f), s1 = (f32x16)(0.f);
#pragma unroll
        for (int c = 0; c < 4; ++c) {
            const short8 ka0 = *(const short8*)&Ks[buf + l5][c * 16 + hf * 8];
            const short8 ka1 = *(const short8*)&Ks[buf + 32 + l5][c * 16 + hf * 8];
            s0 = __builtin_amdgcn_mfma_f32_32x32x16_bf16(ka0, qf[c], s0, 0, 0, 0);
            s1 = __builtin_amdgcn_mfma_f32_32x32x16_bf16(ka1, qf[c], s1, 0, 0, 0);
        }

        // ---- row max over 32 scores/lane (+ cross-half) ----
        float t[8];
#pragma unroll
        for (int i = 0; i < 8; ++i)
            t[i] = fmaxf(fmaxf(s0[i], s0[i + 8]), fmaxf(s1[i], s1[i + 8]));
        float pmax = fmaxf(fmaxf(fmaxf(t[0], t[1]), fmaxf(t[2], t[3])),
                           fmaxf(fmaxf(t[4], t[5]), fmaxf(t[6], t[7])));
        pmax = fmaxf(pmax, __shfl_xor(pmax, 32, 64));

        // ---- defer-max (T13): rescale only when max grew past threshold ----
        if (!__all(pmax - m <= 8.0f)) {
            const float mnew  = fmaxf(m, pmax);
            const float alpha = exp2f(m - mnew);
#pragma unroll
            for (int i = 0; i < 16; ++i) { oacc0[i] *= alpha; oacc1[i] *= alpha; }
            l *= alpha;
            m = mnew;
        }

        // ---- P = exp2(S - m), row sum ----
        float p0[16], p1[16];
#pragma unroll
        for (int i = 0; i < 16; ++i) { p0[i] = exp2f(s0[i] - m); p1[i] = exp2f(s1[i] - m); }
        float sa = 0.f, sb = 0.f, sc_ = 0.f, sd = 0.f;
#pragma unroll
        for (int i = 0; i < 4; ++i) {
            sa += p0[i] + p0[i + 8];
            sb += p0[i + 4] + p0[i + 12];
            sc_ += p1[i] + p1[i + 8];
            sd += p1[i + 4] + p1[i + 12];
        }
        float rs = (sa + sb) + (sc_ + sd);
        rs += __shfl_xor(rs, 32, 64);
        l += rs;

        // ---- pack P -> 4 bf16 B-fragments (cvt_pk + permlane32_swap) ----
        unsigned u0 = cvtpk(p0[0],  p0[1]),  u1 = cvtpk(p0[2],  p0[3]);
        unsigned u2 = cvtpk(p0[4],  p0[5]),  u3 = cvtpk(p0[6],  p0[7]);
        unsigned u4 = cvtpk(p0[8],  p0[9]),  u5 = cvtpk(p0[10], p0[11]);
        unsigned u6 = cvtpk(p0[12], p0[13]), u7 = cvtpk(p0[14], p0[15]);
        unsigned w0 = cvtpk(p1[0],  p1[1]),  w1 = cvtpk(p1[2],  p1[3]);
        unsigned w2 = cvtpk(p1[4],  p1[5]),  w3 = cvtpk(p1[6],  p1[7]);
        unsigned w4 = cvtpk(p1[8],  p1[9]),  w5 = cvtpk(p1[10], p1[11]);
        unsigned w6 = cvtpk(p1[12], p1[13]), w7 = cvtpk(p1[14], p1[15]);
        PLSWAP(u0, u2); PLSWAP(u1, u3); PLSWAP(u4, u6); PLSWAP(u5, u7);
        PLSWAP(w0, w2); PLSWAP(w1, w3); PLSWAP(w4, w6); PLSWAP(w5, w7);
        int4v pb0 = (int4v){ (int)u0, (int)u1, (int)u2, (int)u3 };
        int4v pb1 = (int4v){ (int)u4, (int)u5, (int)u6, (int)u7 };
        int4v pb2 = (int4v){ (int)w0, (int)w1, (int)w2, (int)w3 };
        int4v pb3 = (int4v){ (int)w4, (int)w5, (int)w6, (int)w7 };
        const short8 pbf0 = __builtin_bit_cast(short8, pb0);
        const short8 pbf1 = __builtin_bit_cast(short8, pb1);
        const short8 pbf2 = __builtin_bit_cast(short8, pb2);
        const short8 pbf3 = __builtin_bit_cast(short8, pb3);

        // ---- PV: O += V[d][k-slice] . P ----
        {
            const short8 va0 = *(const short8*)&Vs[buf + l5][hf * 8];
            const short8 va1 = *(const short8*)&Vs[buf + l5][16 + hf * 8];
            const short8 va2 = *(const short8*)&Vs[buf + l5][32 + hf * 8];
            const short8 va3 = *(const short8*)&Vs[buf + l5][48 + hf * 8];
            oacc0 = __builtin_amdgcn_mfma_f32_32x32x16_bf16(va0, pbf0, oacc0, 0, 0, 0);
            oacc0 = __builtin_amdgcn_mfma_f32_32x32x16_bf16(va1, pbf1, oacc0, 0, 0, 0);
            oacc0 = __builtin_amdgcn_mfma_f32_32x32x16_bf16(va2, pbf2, oacc0, 0, 0, 0);
            oacc0 = __builtin_amdgcn_mfma_f32_32x32x16_bf16(va3, pbf3, oacc0, 0, 0, 0);
            const short8 vb0 = *(const short8*)&Vs[buf + 32 + l5][hf * 8];
            const short8 vb1 = *(const short8*)&Vs[buf + 32 + l5][16 + hf * 8];
            const short8 vb2 = *(const short8*)&Vs[buf + 32 + l5][32 + hf * 8];
            const short8 vb3 = *(const short8*)&Vs[buf + 32 + l5][48 + hf * 8];
            oacc1 = __builtin_amdgcn_mfma_f32_32x32x16_bf16(vb0, pbf0, oacc1, 0, 0, 0);
            oacc1 = __builtin_amdgcn_mfma_f32_32x32x16_bf16(vb1, pbf1, oacc1, 0, 0, 0);
            oacc1 = __builtin_amdgcn_mfma_f32_32x32x16_bf16(vb2, pbf2, oacc1, 0, 0, 0);
            oacc1 = __builtin_amdgcn_mfma_f32_32x32x16_bf16(vb3, pbf3, oacc1, 0, 0, 0);
        }

        // ---- write next tile into other buffer; one barrier per iter ----
        if (kc < 15) {
            const int wb = ((kc + 1) & 1) << 6;
            *(short8*)&Ks[wb + sr][sc]     = kr0;
            *(short8*)&Ks[wb + sr][sc + 8] = kr1;
            *(short8*)&Vs[wb + sr][sc]     = vr0;
            *(short8*)&Vs[wb + sr][sc + 8] = vr1;
        }
        __syncthreads();
    }

    // ---- partial epilogue: raw unnormalized O (MFMA layout) + (m,l) ----
    float* Op = Opart + ((((size_t)kvz * 32 + bh) * 16 + qb) * 4 + wave) * 2048;
#pragma unroll
    for (int r = 0; r < 4; ++r) {
        float4 v;
        v.x = oacc0[4*r]; v.y = oacc0[4*r+1]; v.z = oacc0[4*r+2]; v.w = oacc0[4*r+3];
        *(float4*)&Op[r * 256 + lane * 4] = v;
    }
#pragma unroll
    for (int r = 0; r < 4; ++r) {
        float4 v;
        v.x = oacc1[4*r]; v.y = oacc1[4*r+1]; v.z = oacc1[4*r+2]; v.w = oacc1[4*r+3];
        *(float4*)&Op[(4 + r) * 256 + lane * 4] = v;
    }
    if (hf == 0) {
        float2 mv; mv.x = m; mv.y = l;
        Ml[((size_t)kvz * 32 + bh) * 2048 + q0w + l5] = mv;
    }
}

// ---------------------------------------------------------------------------
// LSE-merge of the 2 KV partials -> split-bf16 ctx. One wave per 32-q group.
// ---------------------------------------------------------------------------
__global__ __launch_bounds__(256) void attn_merge(
    const float* __restrict__ Opart, const float2* __restrict__ Ml,
    short* __restrict__ Ch, short* __restrict__ Cl)
{
    __shared__ float epi[4][32][68];          // 34.8 KB
    const int tid = threadIdx.x, wave = tid >> 6, lane = tid & 63;
    const int l5 = lane & 31, hf = lane >> 5;
    const int task = blockIdx.x * 4 + wave;   // 0..2047
    const int bh = task >> 6;
    const int qb = (task >> 2) & 15;
    const int wq = task & 3;
    const int bi = bh >> 4, hi_ = bh & 15;
    const int q0w = qb * 128 + wq * 32;

    const float2 v0 = Ml[(size_t)bh * 2048 + q0w + l5];
    const float2 v1 = Ml[((size_t)32 + bh) * 2048 + q0w + l5];
    const float M  = fmaxf(v0.x, v1.x);
    const float w0 = exp2f(v0.x - M), w1 = exp2f(v1.x - M);
    const float inv = 1.0f / (v0.y * w0 + v1.y * w1);
    const float f0 = w0 * inv, f1 = w1 * inv;

    const float* Op0 = Opart + (((size_t)bh * 16 + qb) * 4 + wq) * 2048;
    const float* Op1 = Opart + ((((size_t)32 + bh) * 16 + qb) * 4 + wq) * 2048;
    float o[32];
#pragma unroll
    for (int r = 0; r < 8; ++r) {
        const float4 a = *(const float4*)&Op0[r * 256 + lane * 4];
        const float4 b = *(const float4*)&Op1[r * 256 + lane * 4];
        o[4*r]   = a.x * f0 + b.x * f1;
        o[4*r+1] = a.y * f0 + b.y * f1;
        o[4*r+2] = a.z * f0 + b.z * f1;
        o[4*r+3] = a.w * f0 + b.w * f1;
    }
#pragma unroll
    for (int r = 0; r < 16; ++r) {
        const int d = (r & 3) + 8 * (r >> 2) + 4 * hf;
        epi[wave][l5][d]      = o[r];
        epi[wave][l5][32 + d] = o[16 + r];
    }
    __builtin_amdgcn_s_waitcnt(0);
#pragma unroll
    for (int pass = 0; pass < 8; ++pass) {
        const int row = pass * 4 + (lane >> 4);
        const int col = (lane & 15) * 4;
        const float4 v = *(const float4*)&epi[wave][row][col];
        const float ov[4] = {v.x, v.y, v.z, v.w};
        short4v hh, ll;
#pragma unroll
        for (int i = 0; i < 4; ++i) {
            hh[i] = f2bf(ov[i]);
            ll[i] = f2bf(ov[i] - bf2f(hh[i]));
        }
        const size_t co = ((size_t)(bi * SEQ + q0w + row)) * D_MODEL + hi_ * HD + col;
        *(short4v*)&Ch[co] = hh;
        *(short4v*)&Cl[co] = ll;
    }
}

// ---------------------------------------------------------------------------
// Output GEMM v2: BM=128 BN=64 BK=32, 256 threads (4 waves 2Mx2N), per-wave
// 64x32. 2-phase schedule, 2x24KB LDS, grid 512. fp32 out.
// ---------------------------------------------------------------------------
#define OBUF_SH 12288          // shorts per LDS buffer (24KB)
#define OO_AL   4096
#define OO_BH   8192
#define OO_BL   10240

__global__ __launch_bounds__(256, 4) void out_gemm2(
    const short* __restrict__ Ah, const short* __restrict__ Al,
    const short* __restrict__ Bh, const short* __restrict__ Bl,
    const float* __restrict__ bias, float* __restrict__ out)
{
    __shared__ __attribute__((aligned(16))) short smem[2 * OBUF_SH];

    const int tid  = threadIdx.x;
    const int wave = tid >> 6, lane = tid & 63;
    const int q4 = lane >> 4, l16 = lane & 15;
    const int wr = wave >> 1, wc = wave & 1;
    const int csw = (q4 ^ ((l16 ^ (l16 >> 2)) & 3)) * 8;

    const int flat = blockIdx.x;
    const int sw = (flat & 7) * 64 + (flat >> 3);
    const int mt = sw & 31, nt = sw >> 5;
    const int m0 = mt * 128, n0 = nt * 64;

    // staging map: 1536 chunks = [Ah 512][Al 512][Bh 256][Bl 256], 6/thread
    const short* srcp[6];
#pragma unroll
    for (int j = 0; j < 6; ++j) {
        const int id = j * 256 + tid;
        int r; const short* mat; int row0;
        if (id < 512)       { r = id >> 2;          mat = Ah; row0 = m0; }
        else if (id < 1024) { r = (id - 512) >> 2;  mat = Al; row0 = m0; }
        else if (id < 1280) { r = (id - 1024) >> 2; mat = Bh; row0 = n0; }
        else                { r = (id - 1280) >> 2; mat = Bl; row0 = n0; }
        const int cg = (id & 3) ^ ((r ^ (r >> 2)) & 3);
        srcp[j] = &mat[(size_t)(row0 + r) * D_MODEL + cg * 8];
    }

    auto stage = [&](int b) {
#pragma unroll
        for (int j = 0; j < 6; ++j) {
            gl16(srcp[j], smem + b * OBUF_SH + (j * 256 + tid) * 8);
            srcp[j] += 32;                  // advance one K-tile
        }
    };

    f32x4 acc[4][2];
#pragma unroll
    for (int i = 0; i < 4; ++i)
#pragma unroll
        for (int j = 0; j < 2; ++j) acc[i][j] = (f32x4){0.f, 0.f, 0.f, 0.f};

    stage(0);
    asm volatile("s_waitcnt vmcnt(0)" ::: "memory");
    __builtin_amdgcn_s_barrier();

    for (int t = 0; t < 32; ++t) {
        const int cur = t & 1;
        const short* base = smem + cur * OBUF_SH;
        const short* Ah_s = base;
        const short* Al_s = base + OO_AL;
        const short* Bh_s = base + OO_BH;
        const short* Bl_s = base + OO_BL;

        // ---- phase 0: B frags + A frags ti=0..1; prefetch next K-tile ----
        short8 bhf[2], blf[2], a0h[2], a0l[2];
#pragma unroll
        for (int n = 0; n < 2; ++n) {
            const int rb = (wc * 32 + n * 16 + l16) * 32 + csw;
            bhf[n] = *(const short8*)(Bh_s + rb);
            blf[n] = *(const short8*)(Bl_s + rb);
        }
#pragma unroll
        for (int ti = 0; ti < 2; ++ti) {
            const int ra = (wr * 64 + ti * 16 + l16) * 32 + csw;
            a0h[ti] = *(const short8*)(Ah_s + ra);
            a0l[ti] = *(const short8*)(Al_s + ra);
        }
        if (t < 31) stage(cur ^ 1);         // stays in flight across barriers
        __builtin_amdgcn_s_barrier();
        asm volatile("s_waitcnt lgkmcnt(0)" ::: "memory");
        __builtin_amdgcn_sched_barrier(0);
        // early-issue phase-1 A frags (complete under phase-0 MFMA)
        short8 a1h[2], a1l[2];
#pragma unroll
        for (int ti = 0; ti < 2; ++ti) {
            const int ra = (wr * 64 + (2 + ti) * 16 + l16) * 32 + csw;
            a1h[ti] = *(const short8*)(Ah_s + ra);
            a1l[ti] = *(const short8*)(Al_s + ra);
        }
        __builtin_amdgcn_sched_barrier(0);
        __builtin_amdgcn_s_setprio(1);
#pragma unroll
        for (int ti = 0; ti < 2; ++ti)
#pragma unroll
            for (int n = 0; n < 2; ++n) {
                acc[ti][n] = __builtin_amdgcn_mfma_f32_16x16x32_bf16(a0h[ti], bhf[n], acc[ti][n], 0, 0, 0);
                acc[ti][n] = __builtin_amdgcn_mfma_f32_16x16x32_bf16(a0h[ti], blf[n], acc[ti][n], 0, 0, 0);
                acc[ti][n] = __builtin_amdgcn_mfma_f32_16x16x32_bf16(a0l[ti], bhf[n], acc[ti][n], 0, 0, 0);
            }
        __builtin_amdgcn_s_setprio(0);
        __builtin_amdgcn_s_barrier();

        // ---- phase 1: A frags ti=2..3 (already in flight) ----
        asm volatile("s_waitcnt lgkmcnt(0)" ::: "memory");
        __builtin_amdgcn_sched_barrier(0);
        __builtin_amdgcn_s_setprio(1);
#pragma unroll
        for (int ti = 0; ti < 2; ++ti)
#pragma unroll
            for (int n = 0; n < 2; ++n) {
                acc[2+ti][n] = __builtin_amdgcn_mfma_f32_16x16x32_bf16(a1h[ti], bhf[n], acc[2+ti][n], 0, 0, 0);
                acc[2+ti][n] = __builtin_amdgcn_mfma_f32_16x16x32_bf16(a1h[ti], blf[n], acc[2+ti][n], 0, 0, 0);
                acc[2+ti][n] = __builtin_amdgcn_mfma_f32_16x16x32_bf16(a1l[ti], bhf[n], acc[2+ti][n], 0, 0, 0);
            }
        __builtin_amdgcn_s_setprio(0);
        asm volatile("s_waitcnt vmcnt(0)" ::: "memory");
        __builtin_amdgcn_s_barrier();
    }

#pragma unroll
    for (int tj = 0; tj < 2; ++tj) {
        const int n = n0 + wc * 32 + tj * 16 + l16;
        const float bv = bias[n];
#pragma unroll
        for (int ti = 0; ti < 4; ++ti) {
            const int mb = m0 + wr * 64 + ti * 16 + q4 * 4;
#pragma unroll
            for (int r = 0; r < 4; ++r)
                out[(size_t)(mb + r) * D_MODEL + n] = acc[ti][tj][r] + bv;
        }
    }
}

// ---------------------------------------------------------------------------
// Workspace layout (peak 61MB, aliasing dead regions):
//   0- 2 Woh | 2- 4 Wol | 4-12 Qb (then Ch) | 12-20 Kb (then Cl) | 20-28 Vtb
//   28-60 Opart (before attn: 28-36 Xh, 36-44 Xl, 44-50 Wh, 50-56 Wl)
//   60-61 Ml
// ---------------------------------------------------------------------------
extern "C" void kernel_launch(void* const* d_in, const int* in_sizes, int n_in,
                              void* d_out, int out_size, void* d_ws, size_t ws_size,
                              hipStream_t stream)
{
    const float* x    = (const float*)d_in[0];
    const float* Wqkv = (const float*)d_in[1];
    const float* bqkv = (const float*)d_in[2];
    const float* Wout = (const float*)d_in[3];
    const float* bout = (const float*)d_in[4];
    float* out = (float*)d_out;

    char* ws = (char*)d_ws;
    short*  Woh   = (short*)(ws);             //  2 MB Wout^T hi
    short*  Wol   = (short*)(ws +  2*MB);     //  2 MB Wout^T lo
    short*  Qb    = (short*)(ws +  4*MB);     //  8 MB [32][2048][64] (pre-scaled)
    short*  Kb    = (short*)(ws + 12*MB);     //  8 MB
    short*  Vtb   = (short*)(ws + 20*MB);     //  8 MB [32][64][2048]
    float*  Opart = (float*)(ws + 28*MB);     // 32 MB [2][32][16][4][2048]
    float2* Ml    = (float2*)(ws + 60*MB);    //  1 MB [2][32][2048]
    short*  Ch    = (short*)(ws +  4*MB);     //  8 MB ctx hi  (aliases Qb)
    short*  Cl    = (short*)(ws + 12*MB);     //  8 MB ctx lo  (aliases Kb)
    short*  Xh    = (short*)(ws + 28*MB);     //  8 MB x hi    (aliases Opart)
    short*  Xl    = (short*)(ws + 36*MB);     //  8 MB x lo
    short*  Wh    = (short*)(ws + 44*MB);     //  6 MB Wqkv^T hi
    short*  Wl    = (short*)(ws + 50*MB);     //  6 MB Wqkv^T lo

    prep<<<6144, 256, 0, stream>>>(x, Wqkv, Wout, Xh, Xl, Wh, Wl, Woh, Wol);
    qkv_gemm8<<<dim3(256), 512, 0, stream>>>(Xh, Xl, Wh, Wl, bqkv, Qb, Kb, Vtb, 0);
    qkv_gemm8<<<dim3(256), 512, 0, stream>>>(Xh, Xl, Wh, Wl, bqkv, Qb, Kb, Vtb, 16);
    attn_tscore<<<dim3(32, 16, 2), 256, 0, stream>>>(Qb, Kb, Vtb, Opart, Ml);
    attn_merge<<<512, 256, 0, stream>>>(Opart, Ml, Ch, Cl);
    out_gemm2<<<dim3(512), 256, 0, stream>>>(Ch, Cl, Woh, Wol, bout, out);
}

// Round 9
// 264.504 us; speedup vs baseline: 1.0209x; 1.0209x over previous
//
#include <hip/hip_runtime.h>

// ---------------------------------------------------------------------------
// MultiHeadAttention, fp32 in/out. 5-kernel pipeline:
//   prep       : Wqkv^T/Wout^T transpose+split-bf16, x split-bf16 (fused)
//   qkv_gemm8  : 128x192 split-bf16 MFMA, 2-phase/K-tile, 2x40KB LDS
//                -> 2 blocks/CU (proven 77.5us); scatters Q,K,Vt bf16
//   attn_tscore: transposed-score flash, KVBLK=64, KV-SPLIT x2. VALU-count
//                cuts: C-seeded (-m) QK MFMA kills per-key subs; l via
//                ones-row MFMA kills the VALU row-sum; defer-max rel-thresh.
//   attn_merge : LSE-merge of 2 partials -> split-bf16 ctx
//   out_gemm2  : 128x64 split-bf16 MFMA, 2-phase, 2x24KB LDS -> fp32 out
// Workspace peak 61MB (aliased dead regions).
// ---------------------------------------------------------------------------

typedef __attribute__((ext_vector_type(8)))  short short8;
typedef __attribute__((ext_vector_type(4)))  short short4v;
typedef __attribute__((ext_vector_type(8)))  float float8;
typedef __attribute__((ext_vector_type(4)))  float f32x4;
typedef __attribute__((ext_vector_type(16))) float f32x16;
typedef __attribute__((ext_vector_type(4)))  int   int4v;

#define D_MODEL 1024
#define NHEAD   16
#define HD      64
#define SEQ     2048
#define N3      (3*D_MODEL)
#define MB      (1024*1024)

static __device__ __forceinline__ float bf2f(short s) {
    unsigned u = ((unsigned)(unsigned short)s) << 16;
    return __builtin_bit_cast(float, u);
}
static __device__ __forceinline__ short f2bf(float f) {
    unsigned u = __builtin_bit_cast(unsigned, f);
    u = (u + 0x7fff + ((u >> 16) & 1)) >> 16;   // RNE
    return (short)u;
}
// hardware packed f32->bf16 (RNE), 1 instr
static __device__ __forceinline__ unsigned cvtpk(float a, float b) {
    unsigned r;
    asm("v_cvt_pk_bf16_f32 %0, %1, %2" : "=v"(r) : "v"(a), "v"(b));
    return r;
}
// in-place cross-half swap: a[32..63] <-> b[0..31]
#define PLSWAP(a, b) asm("v_permlane32_swap_b32 %0, %1" : "+v"(a), "+v"(b))

static __device__ __forceinline__ void gl16(const short* g, short* l) {
    __builtin_amdgcn_global_load_lds(
        (const __attribute__((address_space(1))) unsigned int*)g,
        (__attribute__((address_space(3))) unsigned int*)l, 16, 0, 0);
}

// ---------------------------------------------------------------------------
// prep: blocks [0,2048) split x; [2048,5120) transpose-split Wqkv;
//       [5120,6144) transpose-split Wout.
// ---------------------------------------------------------------------------
__global__ __launch_bounds__(256) void prep(
    const float* __restrict__ x, const float* __restrict__ Wqkv,
    const float* __restrict__ Wout,
    short* __restrict__ Xh, short* __restrict__ Xl,
    short* __restrict__ Wh, short* __restrict__ Wl,
    short* __restrict__ Woh, short* __restrict__ Wol)
{
    __shared__ float tile[32][33];
    const int bid = blockIdx.x;
    const int tid = threadIdx.x;

    if (bid < 2048) {                        // ---- split x ----
        const int i = (bid * 256 + tid) * 8;
        const float8 v = *(const float8*)&x[i];
        short8 h, l;
#pragma unroll
        for (int j = 0; j < 8; ++j) {
            h[j] = f2bf(v[j]);
            l[j] = f2bf(v[j] - bf2f(h[j]));
        }
        *(short8*)&Xh[i] = h;
        *(short8*)&Xl[i] = l;
        return;
    }

    // ---- transpose + split a weight matrix ----
    const float* in; short *hi, *lo; int K, N, bx, by;
    if (bid < 5120) {
        const int b2 = bid - 2048;
        in = Wqkv; hi = Wh; lo = Wl; K = D_MODEL; N = N3;
        bx = b2 % 96; by = b2 / 96;
    } else {
        const int b3 = bid - 5120;
        in = Wout; hi = Woh; lo = Wol; K = D_MODEL; N = D_MODEL;
        bx = b3 & 31; by = b3 >> 5;
    }
    const int n0 = bx * 32, k0 = by * 32;
    const int tx = tid & 31, ty = tid >> 5;
#pragma unroll
    for (int i = 0; i < 4; ++i)
        tile[ty + 8*i][tx] = in[(k0 + ty + 8*i) * N + (n0 + tx)];
    __syncthreads();
#pragma unroll
    for (int i = 0; i < 4; ++i) {
        const float v  = tile[tx][ty + 8*i];
        const short vh = f2bf(v);
        const short vl = f2bf(v - bf2f(vh));
        const int idx  = (n0 + ty + 8*i) * K + (k0 + tx);
        hi[idx] = vh;
        lo[idx] = vl;
    }
}

// ---------------------------------------------------------------------------
// QKV GEMM (proven R5/R7). BM=128 BN=192 BK=32, 512 threads (8 waves 2Mx4N),
// per-wave output 64x48. LDS: 2 x 40KB buffers -> 2 blocks/CU.
// ---------------------------------------------------------------------------
#define QBUF_SH 20480          // shorts per LDS buffer (40KB)
#define OFF_AL  4096
#define OFF_BH  8192
#define OFF_BL  14336

__global__ __launch_bounds__(512, 4) void qkv_gemm8(
    const short* __restrict__ Xh, const short* __restrict__ Xl,
    const short* __restrict__ Bh, const short* __restrict__ Bl,
    const float* __restrict__ bias,
    short* __restrict__ Qo, short* __restrict__ Ko, short* __restrict__ Vt)
{
    __shared__ __attribute__((aligned(16))) short smem[2 * QBUF_SH];

    const int tid  = threadIdx.x;
    const int wave = tid >> 6, lane = tid & 63;
    const int q4 = lane >> 4, l16 = lane & 15;
    const int wr = wave >> 2, wc = wave & 3;
    const int csw = (q4 ^ ((l16 ^ (l16 >> 2)) & 3)) * 8;

    const int flat = blockIdx.x;
    const int sw = (flat & 7) * 64 + (flat >> 3);
    const int mt = sw & 31, nt = sw >> 5;
    const int m0 = mt * 128, n0 = nt * 192;

    // staging map: 2560 chunks = [Ah 512][Al 512][Bh 768][Bl 768], 5/thread
    const short* srcp[5];
#pragma unroll
    for (int j = 0; j < 5; ++j) {
        const int id = j * 512 + tid;
        int r; const short* mat; int row0;
        if (id < 512)       { r = id >> 2;          mat = Xh; row0 = m0; }
        else if (id < 1024) { r = (id - 512) >> 2;  mat = Xl; row0 = m0; }
        else if (id < 1792) { r = (id - 1024) >> 2; mat = Bh; row0 = n0; }
        else                { r = (id - 1792) >> 2; mat = Bl; row0 = n0; }
        const int cg = (id & 3) ^ ((r ^ (r >> 2)) & 3);
        srcp[j] = &mat[(size_t)(row0 + r) * D_MODEL + cg * 8];
    }

    auto stage = [&](int b) {
#pragma unroll
        for (int j = 0; j < 5; ++j) {
            gl16(srcp[j], smem + b * QBUF_SH + (j * 512 + tid) * 8);
            srcp[j] += 32;                  // advance one K-tile
        }
    };

    f32x4 acc[4][3];
#pragma unroll
    for (int i = 0; i < 4; ++i)
#pragma unroll
        for (int j = 0; j < 3; ++j) acc[i][j] = (f32x4){0.f, 0.f, 0.f, 0.f};

    stage(0);
    asm volatile("s_waitcnt vmcnt(0)" ::: "memory");
    __builtin_amdgcn_s_barrier();

    for (int t = 0; t < 32; ++t) {
        const int cur = t & 1;
        const short* base = smem + cur * QBUF_SH;
        const short* Ah_s = base;
        const short* Al_s = base + OFF_AL;
        const short* Bh_s = base + OFF_BH;
        const short* Bl_s = base + OFF_BL;

        // ---- phase 0: B frags + A frags ti=0..1; prefetch next K-tile ----
        short8 bhf[3], blf[3], a0h[2], a0l[2];
#pragma unroll
        for (int n = 0; n < 3; ++n) {
            const int rb = (wc * 48 + n * 16 + l16) * 32 + csw;
            bhf[n] = *(const short8*)(Bh_s + rb);
            blf[n] = *(const short8*)(Bl_s + rb);
        }
#pragma unroll
        for (int ti = 0; ti < 2; ++ti) {
            const int ra = (wr * 64 + ti * 16 + l16) * 32 + csw;
            a0h[ti] = *(const short8*)(Ah_s + ra);
            a0l[ti] = *(const short8*)(Al_s + ra);
        }
        if (t < 31) stage(cur ^ 1);         // stays in flight across barriers
        __builtin_amdgcn_s_barrier();
        asm volatile("s_waitcnt lgkmcnt(0)" ::: "memory");
        __builtin_amdgcn_sched_barrier(0);
        // early-issue phase-1 A frags (complete under phase-0 MFMA)
        short8 a1h[2], a1l[2];
#pragma unroll
        for (int ti = 0; ti < 2; ++ti) {
            const int ra = (wr * 64 + (2 + ti) * 16 + l16) * 32 + csw;
            a1h[ti] = *(const short8*)(Ah_s + ra);
            a1l[ti] = *(const short8*)(Al_s + ra);
        }
        __builtin_amdgcn_sched_barrier(0);
        __builtin_amdgcn_s_setprio(1);
#pragma unroll
        for (int ti = 0; ti < 2; ++ti)
#pragma unroll
            for (int n = 0; n < 3; ++n) {
                acc[ti][n] = __builtin_amdgcn_mfma_f32_16x16x32_bf16(a0h[ti], bhf[n], acc[ti][n], 0, 0, 0);
                acc[ti][n] = __builtin_amdgcn_mfma_f32_16x16x32_bf16(a0h[ti], blf[n], acc[ti][n], 0, 0, 0);
                acc[ti][n] = __builtin_amdgcn_mfma_f32_16x16x32_bf16(a0l[ti], bhf[n], acc[ti][n], 0, 0, 0);
            }
        __builtin_amdgcn_s_setprio(0);
        __builtin_amdgcn_s_barrier();

        // ---- phase 1: A frags ti=2..3 (already in flight) ----
        asm volatile("s_waitcnt lgkmcnt(0)" ::: "memory");
        __builtin_amdgcn_sched_barrier(0);
        __builtin_amdgcn_s_setprio(1);
#pragma unroll
        for (int ti = 0; ti < 2; ++ti)
#pragma unroll
            for (int n = 0; n < 3; ++n) {
                acc[2+ti][n] = __builtin_amdgcn_mfma_f32_16x16x32_bf16(a1h[ti], bhf[n], acc[2+ti][n], 0, 0, 0);
                acc[2+ti][n] = __builtin_amdgcn_mfma_f32_16x16x32_bf16(a1h[ti], blf[n], acc[2+ti][n], 0, 0, 0);
                acc[2+ti][n] = __builtin_amdgcn_mfma_f32_16x16x32_bf16(a1l[ti], bhf[n], acc[2+ti][n], 0, 0, 0);
            }
        __builtin_amdgcn_s_setprio(0);
        asm volatile("s_waitcnt vmcnt(0)" ::: "memory");
        __builtin_amdgcn_s_barrier();
    }

    // epilogue: scatter Q (pre-scaled), K, Vt
    const float SCALE_Q = 0.125f * 1.4426950408889634f;
#pragma unroll
    for (int tj = 0; tj < 3; ++tj) {
        const int jj = wc * 48 + tj * 16 + l16;   // 0..191 within head
        const int n  = nt * 192 + jj;
        const float bv = bias[n];
#pragma unroll
        for (int ti = 0; ti < 4; ++ti) {
            const int mb = m0 + wr * 64 + ti * 16 + q4 * 4;
            const int b = mb >> 11;
            const int s = mb & 2047;
            const int bh_ = b * NHEAD + nt;
            if (jj >= 128) {                      // Vt: s is fast axis -> short4
                short4v v4;
#pragma unroll
                for (int r = 0; r < 4; ++r) v4[r] = f2bf(acc[ti][tj][r] + bv);
                *(short4v*)&Vt[(bh_ * HD + (jj - 128)) * SEQ + s] = v4;
            } else if (jj < 64) {
#pragma unroll
                for (int r = 0; r < 4; ++r)
                    Qo[(bh_ * SEQ + s + r) * HD + jj] = f2bf((acc[ti][tj][r] + bv) * SCALE_Q);
            } else {
#pragma unroll
                for (int r = 0; r < 4; ++r)
                    Ko[(bh_ * SEQ + s + r) * HD + (jj - 64)] = f2bf(acc[ti][tj][r] + bv);
            }
        }
    }
}

// ---------------------------------------------------------------------------
// Transposed-score flash attention, KV-SPLIT x2. Grid (32 bh, 16 qb, 2 kvz).
// VALU cuts: scores arrive pre-shifted (C = -m seed, mseed kept live);
// defer-max on RELATIVE threshold (m init 0, never -inf: rel-space add needs
// finite m); row-sum l computed by ones-row MFMA on the idle matrix pipe.
// ---------------------------------------------------------------------------
__global__ __launch_bounds__(256, 2) void attn_tscore(
    const short* __restrict__ Q, const short* __restrict__ K,
    const short* __restrict__ Vt,
    float* __restrict__ Opart, float2* __restrict__ Ml)
{
    __shared__ __attribute__((aligned(16))) char smem[36864];
    short (*Ks)[72] = (short(*)[72])smem;                 // [2*64 key][64 d + pad]
    short (*Vs)[72] = (short(*)[72])(smem + 18432);       // [2*64 d][64 key + pad]

    const int bh  = blockIdx.x;               // 0..31
    const int qb  = blockIdx.y;               // 0..15
    const int kvz = blockIdx.z;               // 0..1

    const short* Qp  = Q  + (size_t)bh * SEQ * HD;
    const short* Kp  = K  + (size_t)bh * SEQ * HD + (size_t)kvz * 1024 * HD;
    const short* Vtp = Vt + (size_t)bh * HD * SEQ + (size_t)kvz * 1024;

    const int tid  = threadIdx.x;
    const int wave = tid >> 6, lane = tid & 63;
    const int l5 = lane & 31, hf = lane >> 5;
    const int q0w = qb * 128 + wave * 32;

    short8 qf[4];
#pragma unroll
    for (int c = 0; c < 4; ++c)
        qf[c] = *(const short8*)&Qp[(q0w + l5) * HD + c * 16 + hf * 8];

    short8 one8;
#pragma unroll
    for (int i = 0; i < 8; ++i) one8[i] = (short)0x3F80;  // bf16 1.0

    f32x16 oacc0 = (f32x16)(0.f), oacc1 = (f32x16)(0.f);
    f32x16 lacc  = (f32x16)(0.f);             // all rows = running sum of P
    f32x16 mseed = (f32x16)(0.f);             // splat(-m), live across iters
    float m = 0.f;                            // running max (finite init!)

    // staging: 256 threads cover 64 rows x 64 cols (2x short8 each for K and V)
    const int sr = tid >> 2;          // 0..63
    const int sc = (tid & 3) * 16;    // 0,16,32,48

    short8 kr0 = *(const short8*)&Kp[sr * HD + sc];
    short8 kr1 = *(const short8*)&Kp[sr * HD + sc + 8];
    short8 vr0 = *(const short8*)&Vtp[sr * SEQ + sc];
    short8 vr1 = *(const short8*)&Vtp[sr * SEQ + sc + 8];
    *(short8*)&Ks[sr][sc]     = kr0;
    *(short8*)&Ks[sr][sc + 8] = kr1;
    *(short8*)&Vs[sr][sc]     = vr0;
    *(short8*)&Vs[sr][sc + 8] = vr1;
    __syncthreads();

    for (int kc = 0; kc < 16; ++kc) {
        const int buf = (kc & 1) << 6;

        // issue next tile's global loads (hidden under this tile's compute)
        if (kc < 15) {
            const int nkb = (kc + 1) << 6;
            kr0 = *(const short8*)&Kp[(nkb + sr) * HD + sc];
            kr1 = *(const short8*)&Kp[(nkb + sr) * HD + sc + 8];
            vr0 = *(const short8*)&Vtp[sr * SEQ + nkb + sc];
            vr1 = *(const short8*)&Vtp[sr * SEQ + nkb + sc + 8];
        }

        // ---- scores (pre-shifted by -m via C-seed): two 32-key tiles ----
        f32x16 s0, s1;
        {
            const short8 ka0 = *(const short8*)&Ks[buf + l5][hf * 8];
            const short8 ka1 = *(const short8*)&Ks[buf + 32 + l5][hf * 8];
            s0 = __builtin_amdgcn_mfma_f32_32x32x16_bf16(ka0, qf[0], mseed, 0, 0, 0);
            s1 = __builtin_amdgcn_mfma_f32_32x32x16_bf16(ka1, qf[0], mseed, 0, 0, 0);
        }
#pragma unroll
        for (int c = 1; c < 4; ++c) {
            const short8 ka0 = *(const short8*)&Ks[buf + l5][c * 16 + hf * 8];
            const short8 ka1 = *(const short8*)&Ks[buf + 32 + l5][c * 16 + hf * 8];
            s0 = __builtin_amdgcn_mfma_f32_32x32x16_bf16(ka0, qf[c], s0, 0, 0, 0);
            s1 = __builtin_amdgcn_mfma_f32_32x32x16_bf16(ka1, qf[c], s1, 0, 0, 0);
        }

        // ---- relative row max over 32 scores/lane (+ cross-half) ----
        float t[8];
#pragma unroll
        for (int i = 0; i < 8; ++i)
            t[i] = fmaxf(fmaxf(s0[i], s0[i + 8]), fmaxf(s1[i], s1[i + 8]));
        float pmax = fmaxf(fmaxf(fmaxf(t[0], t[1]), fmaxf(t[2], t[3])),
                           fmaxf(fmaxf(t[4], t[5]), fmaxf(t[6], t[7])));
        pmax = fmaxf(pmax, __shfl_xor(pmax, 32, 64));

        // ---- defer-max (T13, relative): rescale only past threshold ----
        if (!__all(pmax <= 8.0f)) {
            const float delta = fmaxf(pmax, 0.0f);
            const float alpha = exp2f(-delta);
#pragma unroll
            for (int i = 0; i < 16; ++i) {
                oacc0[i] *= alpha; oacc1[i] *= alpha; lacc[i] *= alpha;
            }
            m += delta;
#pragma unroll
            for (int i = 0; i < 16; ++i) mseed[i] = -m;
#pragma unroll
            for (int i = 0; i < 16; ++i) { s0[i] -= delta; s1[i] -= delta; }
        }

        // ---- P = exp2(s_rel) (no subs on common path) ----
        float p0[16], p1[16];
#pragma unroll
        for (int i = 0; i < 16; ++i) { p0[i] = exp2f(s0[i]); p1[i] = exp2f(s1[i]); }

        // ---- pack P -> 4 bf16 B-fragments (cvt_pk + permlane32_swap) ----
        unsigned u0 = cvtpk(p0[0],  p0[1]),  u1 = cvtpk(p0[2],  p0[3]);
        unsigned u2 = cvtpk(p0[4],  p0[5]),  u3 = cvtpk(p0[6],  p0[7]);
        unsigned u4 = cvtpk(p0[8],  p0[9]),  u5 = cvtpk(p0[10], p0[11]);
        unsigned u6 = cvtpk(p0[12], p0[13]), u7 = cvtpk(p0[14], p0[15]);
        unsigned w0 = cvtpk(p1[0],  p1[1]),  w1 = cvtpk(p1[2],  p1[3]);
        unsigned w2 = cvtpk(p1[4],  p1[5]),  w3 = cvtpk(p1[6],  p1[7]);
        unsigned w4 = cvtpk(p1[8],  p1[9]),  w5 = cvtpk(p1[10], p1[11]);
        unsigned w6 = cvtpk(p1[12], p1[13]), w7 = cvtpk(p1[14], p1[15]);
        PLSWAP(u0, u2); PLSWAP(u1, u3); PLSWAP(u4, u6); PLSWAP(u5, u7);
        PLSWAP(w0, w2); PLSWAP(w1, w3); PLSWAP(w4, w6); PLSWAP(w5, w7);
        int4v pb0 = (int4v){ (int)u0, (int)u1, (int)u2, (int)u3 };
        int4v pb1 = (int4v){ (int)u4, (int)u5, (int)u6, (int)u7 };
        int4v pb2 = (int4v){ (int)w0, (int)w1, (int)w2, (int)w3 };
        int4v pb3 = (int4v){ (int)w4, (int)w5, (int)w6, (int)w7 };
        const short8 pbf0 = __builtin_bit_cast(short8, pb0);
        const short8 pbf1 = __builtin_bit_cast(short8, pb1);
        const short8 pbf2 = __builtin_bit_cast(short8, pb2);
        const short8 pbf3 = __builtin_bit_cast(short8, pb3);

        // ---- PV: O += V[d][k-slice] . P ; l-row via ones MFMA ----
        {
            const short8 va0 = *(const short8*)&Vs[buf + l5][hf * 8];
            const short8 va1 = *(const short8*)&Vs[buf + l5][16 + hf * 8];
            const short8 va2 = *(const short8*)&Vs[buf + l5][32 + hf * 8];
            const short8 va3 = *(const short8*)&Vs[buf + l5][48 + hf * 8];
            oacc0 = __builtin_amdgcn_mfma_f32_32x32x16_bf16(va0, pbf0, oacc0, 0, 0, 0);
            oacc0 = __builtin_amdgcn_mfma_f32_32x32x16_bf16(va1, pbf1, oacc0, 0, 0, 0);
            oacc0 = __builtin_amdgcn_mfma_f32_32x32x16_bf16(va2, pbf2, oacc0, 0, 0, 0);
            oacc0 = __builtin_amdgcn_mfma_f32_32x32x16_bf16(va3, pbf3, oacc0, 0, 0, 0);
            const short8 vb0 = *(const short8*)&Vs[buf + 32 + l5][hf * 8];
            const short8 vb1 = *(const short8*)&Vs[buf + 32 + l5][16 + hf * 8];
            const short8 vb2 = *(const short8*)&Vs[buf + 32 + l5][32 + hf * 8];
            const short8 vb3 = *(const short8*)&Vs[buf + 32 + l5][48 + hf * 8];
            oacc1 = __builtin_amdgcn_mfma_f32_32x32x16_bf16(vb0, pbf0, oacc1, 0, 0, 0);
            oacc1 = __builtin_amdgcn_mfma_f32_32x32x16_bf16(vb1, pbf1, oacc1, 0, 0, 0);
            oacc1 = __builtin_amdgcn_mfma_f32_32x32x16_bf16(vb2, pbf2, oacc1, 0, 0, 0);
            oacc1 = __builtin_amdgcn_mfma_f32_32x32x16_bf16(vb3, pbf3, oacc1, 0, 0, 0);
            lacc  = __builtin_amdgcn_mfma_f32_32x32x16_bf16(one8, pbf0, lacc, 0, 0, 0);
            lacc  = __builtin_amdgcn_mfma_f32_32x32x16_bf16(one8, pbf1, lacc, 0, 0, 0);
            lacc  = __builtin_amdgcn_mfma_f32_32x32x16_bf16(one8, pbf2, lacc, 0, 0, 0);
            lacc  = __builtin_amdgcn_mfma_f32_32x32x16_bf16(one8, pbf3, lacc, 0, 0, 0);
        }

        // ---- write next tile into other buffer; one barrier per iter ----
        if (kc < 15) {
            const int wb = ((kc + 1) & 1) << 6;
            *(short8*)&Ks[wb + sr][sc]     = kr0;
            *(short8*)&Ks[wb + sr][sc + 8] = kr1;
            *(short8*)&Vs[wb + sr][sc]     = vr0;
            *(short8*)&Vs[wb + sr][sc + 8] = vr1;
        }
        __syncthreads();
    }

    // ---- partial epilogue: raw unnormalized O (MFMA layout) + (m,l) ----
    float* Op = Opart + ((((size_t)kvz * 32 + bh) * 16 + qb) * 4 + wave) * 2048;
#pragma unroll
    for (int r = 0; r < 4; ++r) {
        float4 v;
        v.x = oacc0[4*r]; v.y = oacc0[4*r+1]; v.z = oacc0[4*r+2]; v.w = oacc0[4*r+3];
        *(float4*)&Op[r * 256 + lane * 4] = v;
    }
#pragma unroll
    for (int r = 0; r < 4; ++r) {
        float4 v;
        v.x = oacc1[4*r]; v.y = oacc1[4*r+1]; v.z = oacc1[4*r+2]; v.w = oacc1[4*r+3];
        *(float4*)&Op[(4 + r) * 256 + lane * 4] = v;
    }
    if (hf == 0) {
        float2 mv; mv.x = m; mv.y = lacc[0];
        Ml[((size_t)kvz * 32 + bh) * 2048 + q0w + l5] = mv;
    }
}

// ---------------------------------------------------------------------------
// LSE-merge of the 2 KV partials -> split-bf16 ctx. One wave per 32-q group.
// ---------------------------------------------------------------------------
__global__ __launch_bounds__(256) void attn_merge(
    const float* __restrict__ Opart, const float2* __restrict__ Ml,
    short* __restrict__ Ch, short* __restrict__ Cl)
{
    __shared__ float epi[4][32][68];          // 34.8 KB
    const int tid = threadIdx.x, wave = tid >> 6, lane = tid & 63;
    const int l5 = lane & 31, hf = lane >> 5;
    const int task = blockIdx.x * 4 + wave;   // 0..2047
    const int bh = task >> 6;
    const int qb = (task >> 2) & 15;
    const int wq = task & 3;
    const int bi = bh >> 4, hi_ = bh & 15;
    const int q0w = qb * 128 + wq * 32;

    const float2 v0 = Ml[(size_t)bh * 2048 + q0w + l5];
    const float2 v1 = Ml[((size_t)32 + bh) * 2048 + q0w + l5];
    const float M  = fmaxf(v0.x, v1.x);
    const float w0 = exp2f(v0.x - M), w1 = exp2f(v1.x - M);
    const float inv = 1.0f / (v0.y * w0 + v1.y * w1);
    const float f0 = w0 * inv, f1 = w1 * inv;

    const float* Op0 = Opart + (((size_t)bh * 16 + qb) * 4 + wq) * 2048;
    const float* Op1 = Opart + ((((size_t)32 + bh) * 16 + qb) * 4 + wq) * 2048;
    float o[32];
#pragma unroll
    for (int r = 0; r < 8; ++r) {
        const float4 a = *(const float4*)&Op0[r * 256 + lane * 4];
        const float4 b = *(const float4*)&Op1[r * 256 + lane * 4];
        o[4*r]   = a.x * f0 + b.x * f1;
        o[4*r+1] = a.y * f0 + b.y * f1;
        o[4*r+2] = a.z * f0 + b.z * f1;
        o[4*r+3] = a.w * f0 + b.w * f1;
    }
#pragma unroll
    for (int r = 0; r < 16; ++r) {
        const int d = (r & 3) + 8 * (r >> 2) + 4 * hf;
        epi[wave][l5][d]      = o[r];
        epi[wave][l5][32 + d] = o[16 + r];
    }
    __builtin_amdgcn_s_waitcnt(0);
#pragma unroll
    for (int pass = 0; pass < 8; ++pass) {
        const int row = pass * 4 + (lane >> 4);
        const int col = (lane & 15) * 4;
        const float4 v = *(const float4*)&epi[wave][row][col];
        const float ov[4] = {v.x, v.y, v.z, v.w};
        short4v hh, ll;
#pragma unroll
        for (int i = 0; i < 4; ++i) {
            hh[i] = f2bf(ov[i]);
            ll[i] = f2bf(ov[i] - bf2f(hh[i]));
        }
        const size_t co = ((size_t)(bi * SEQ + q0w + row)) * D_MODEL + hi_ * HD + col;
        *(short4v*)&Ch[co] = hh;
        *(short4v*)&Cl[co] = ll;
    }
}

// ---------------------------------------------------------------------------
// Output GEMM v2: BM=128 BN=64 BK=32, 256 threads (4 waves 2Mx2N), per-wave
// 64x32. 2-phase schedule, 2x24KB LDS, grid 512. fp32 out.
// ---------------------------------------------------------------------------
#define OBUF_SH 12288          // shorts per LDS buffer (24KB)
#define OO_AL   4096
#define OO_BH   8192
#define OO_BL   10240

__global__ __launch_bounds__(256, 4) void out_gemm2(
    const short* __restrict__ Ah, const short* __restrict__ Al,
    const short* __restrict__ Bh, const short* __restrict__ Bl,
    const float* __restrict__ bias, float* __restrict__ out)
{
    __shared__ __attribute__((aligned(16))) short smem[2 * OBUF_SH];

    const int tid  = threadIdx.x;
    const int wave = tid >> 6, lane = tid & 63;
    const int q4 = lane >> 4, l16 = lane & 15;
    const int wr = wave >> 1, wc = wave & 1;
    const int csw = (q4 ^ ((l16 ^ (l16 >> 2)) & 3)) * 8;

    const int flat = blockIdx.x;
    const int sw = (flat & 7) * 64 + (flat >> 3);
    const int mt = sw & 31, nt = sw >> 5;
    const int m0 = mt * 128, n0 = nt * 64;

    // staging map: 1536 chunks = [Ah 512][Al 512][Bh 256][Bl 256], 6/thread
    const short* srcp[6];
#pragma unroll
    for (int j = 0; j < 6; ++j) {
        const int id = j * 256 + tid;
        int r; const short* mat; int row0;
        if (id < 512)       { r = id >> 2;          mat = Ah; row0 = m0; }
        else if (id < 1024) { r = (id - 512) >> 2;  mat = Al; row0 = m0; }
        else if (id < 1280) { r = (id - 1024) >> 2; mat = Bh; row0 = n0; }
        else                { r = (id - 1280) >> 2; mat = Bl; row0 = n0; }
        const int cg = (id & 3) ^ ((r ^ (r >> 2)) & 3);
        srcp[j] = &mat[(size_t)(row0 + r) * D_MODEL + cg * 8];
    }

    auto stage = [&](int b) {
#pragma unroll
        for (int j = 0; j < 6; ++j) {
            gl16(srcp[j], smem + b * OBUF_SH + (j * 256 + tid) * 8);
            srcp[j] += 32;                  // advance one K-tile
        }
    };

    f32x4 acc[4][2];
#pragma unroll
    for (int i = 0; i < 4; ++i)
#pragma unroll
        for (int j = 0; j < 2; ++j) acc[i][j] = (f32x4){0.f, 0.f, 0.f, 0.f};

    stage(0);
    asm volatile("s_waitcnt vmcnt(0)" ::: "memory");
    __builtin_amdgcn_s_barrier();

    for (int t = 0; t < 32; ++t) {
        const int cur = t & 1;
        const short* base = smem + cur * OBUF_SH;
        const short* Ah_s = base;
        const short* Al_s = base + OO_AL;
        const short* Bh_s = base + OO_BH;
        const short* Bl_s = base + OO_BL;

        // ---- phase 0: B frags + A frags ti=0..1; prefetch next K-tile ----
        short8 bhf[2], blf[2], a0h[2], a0l[2];
#pragma unroll
        for (int n = 0; n < 2; ++n) {
            const int rb = (wc * 32 + n * 16 + l16) * 32 + csw;
            bhf[n] = *(const short8*)(Bh_s + rb);
            blf[n] = *(const short8*)(Bl_s + rb);
        }
#pragma unroll
        for (int ti = 0; ti < 2; ++ti) {
            const int ra = (wr * 64 + ti * 16 + l16) * 32 + csw;
            a0h[ti] = *(const short8*)(Ah_s + ra);
            a0l[ti] = *(const short8*)(Al_s + ra);
        }
        if (t < 31) stage(cur ^ 1);         // stays in flight across barriers
        __builtin_amdgcn_s_barrier();
        asm volatile("s_waitcnt lgkmcnt(0)" ::: "memory");
        __builtin_amdgcn_sched_barrier(0);
        // early-issue phase-1 A frags (complete under phase-0 MFMA)
        short8 a1h[2], a1l[2];
#pragma unroll
        for (int ti = 0; ti < 2; ++ti) {
            const int ra = (wr * 64 + (2 + ti) * 16 + l16) * 32 + csw;
            a1h[ti] = *(const short8*)(Ah_s + ra);
            a1l[ti] = *(const short8*)(Al_s + ra);
        }
        __builtin_amdgcn_sched_barrier(0);
        __builtin_amdgcn_s_setprio(1);
#pragma unroll
        for (int ti = 0; ti < 2; ++ti)
#pragma unroll
            for (int n = 0; n < 2; ++n) {
                acc[ti][n] = __builtin_amdgcn_mfma_f32_16x16x32_bf16(a0h[ti], bhf[n], acc[ti][n], 0, 0, 0);
                acc[ti][n] = __builtin_amdgcn_mfma_f32_16x16x32_bf16(a0h[ti], blf[n], acc[ti][n], 0, 0, 0);
                acc[ti][n] = __builtin_amdgcn_mfma_f32_16x16x32_bf16(a0l[ti], bhf[n], acc[ti][n], 0, 0, 0);
            }
        __builtin_amdgcn_s_setprio(0);
        __builtin_amdgcn_s_barrier();

        // ---- phase 1: A frags ti=2..3 (already in flight) ----
        asm volatile("s_waitcnt lgkmcnt(0)" ::: "memory");
        __builtin_amdgcn_sched_barrier(0);
        __builtin_amdgcn_s_setprio(1);
#pragma unroll
        for (int ti = 0; ti < 2; ++ti)
#pragma unroll
            for (int n = 0; n < 2; ++n) {
                acc[2+ti][n] = __builtin_amdgcn_mfma_f32_16x16x32_bf16(a1h[ti], bhf[n], acc[2+ti][n], 0, 0, 0);
                acc[2+ti][n] = __builtin_amdgcn_mfma_f32_16x16x32_bf16(a1h[ti], blf[n], acc[2+ti][n], 0, 0, 0);
                acc[2+ti][n] = __builtin_amdgcn_mfma_f32_16x16x32_bf16(a1l[ti], bhf[n], acc[2+ti][n], 0, 0, 0);
            }
        __builtin_amdgcn_s_setprio(0);
        asm volatile("s_waitcnt vmcnt(0)" ::: "memory");
        __builtin_amdgcn_s_barrier();
    }

#pragma unroll
    for (int tj = 0; tj < 2; ++tj) {
        const int n = n0 + wc * 32 + tj * 16 + l16;
        const float bv = bias[n];
#pragma unroll
        for (int ti = 0; ti < 4; ++ti) {
            const int mb = m0 + wr * 64 + ti * 16 + q4 * 4;
#pragma unroll
            for (int r = 0; r < 4; ++r)
                out[(size_t)(mb + r) * D_MODEL + n] = acc[ti][tj][r] + bv;
        }
    }
}

// ---------------------------------------------------------------------------
// Workspace layout (peak 61MB, aliasing dead regions):
//   0- 2 Woh | 2- 4 Wol | 4-12 Qb (then Ch) | 12-20 Kb (then Cl) | 20-28 Vtb
//   28-60 Opart (before attn: 28-36 Xh, 36-44 Xl, 44-50 Wh, 50-56 Wl)
//   60-61 Ml
// ---------------------------------------------------------------------------
extern "C" void kernel_launch(void* const* d_in, const int* in_sizes, int n_in,
                              void* d_out, int out_size, void* d_ws, size_t ws_size,
                              hipStream_t stream)
{
    const float* x    = (const float*)d_in[0];
    const float* Wqkv = (const float*)d_in[1];
    const float* bqkv = (const float*)d_in[2];
    const float* Wout = (const float*)d_in[3];
    const float* bout = (const float*)d_in[4];
    float* out = (float*)d_out;

    char* ws = (char*)d_ws;
    short*  Woh   = (short*)(ws);             //  2 MB Wout^T hi
    short*  Wol   = (short*)(ws +  2*MB);     //  2 MB Wout^T lo
    short*  Qb    = (short*)(ws +  4*MB);     //  8 MB [32][2048][64] (pre-scaled)
    short*  Kb    = (short*)(ws + 12*MB);     //  8 MB
    short*  Vtb   = (short*)(ws + 20*MB);     //  8 MB [32][64][2048]
    float*  Opart = (float*)(ws + 28*MB);     // 32 MB [2][32][16][4][2048]
    float2* Ml    = (float2*)(ws + 60*MB);    //  1 MB [2][32][2048]
    short*  Ch    = (short*)(ws +  4*MB);     //  8 MB ctx hi  (aliases Qb)
    short*  Cl    = (short*)(ws + 12*MB);     //  8 MB ctx lo  (aliases Kb)
    short*  Xh    = (short*)(ws + 28*MB);     //  8 MB x hi    (aliases Opart)
    short*  Xl    = (short*)(ws + 36*MB);     //  8 MB x lo
    short*  Wh    = (short*)(ws + 44*MB);     //  6 MB Wqkv^T hi
    short*  Wl    = (short*)(ws + 50*MB);     //  6 MB Wqkv^T lo

    prep<<<6144, 256, 0, stream>>>(x, Wqkv, Wout, Xh, Xl, Wh, Wl, Woh, Wol);
    qkv_gemm8<<<dim3(512), 512, 0, stream>>>(Xh, Xl, Wh, Wl, bqkv, Qb, Kb, Vtb);
    attn_tscore<<<dim3(32, 16, 2), 256, 0, stream>>>(Qb, Kb, Vtb, Opart, Ml);
    attn_merge<<<512, 256, 0, stream>>>(Opart, Ml, Ch, Cl);
    out_gemm2<<<dim3(512), 256, 0, stream>>>(Ch, Cl, Woh, Wol, bout, out);
}

// Round 11
// 264.199 us; speedup vs baseline: 1.0221x; 1.0012x over previous
//
#include <hip/hip_runtime.h>

// ---------------------------------------------------------------------------
// MultiHeadAttention, fp32 in/out. 5-kernel pipeline:
//   prep       : Wqkv^T/Wout^T transpose+split-bf16, x split-bf16 (fused)
//   qkv_gemm8  : 128x192 split-bf16 MFMA, counted-vmcnt schedule with the
//                CERTIFY barrier (vmcnt(5) BEFORE barrier B - per-wave vmcnt
//                + barrier = collective guarantee; R9 had them inverted ->
//                race), 2x40KB LDS -> 2 blocks/CU; scatters Q,K,Vt bf16
//   attn_tscore: transposed-score flash, KVBLK=64, KV-SPLIT x2; C-seeded
//                (-m) QK MFMA, l via ones-row MFMA, defer-max rel-thresh
//   attn_merge : LSE-merge of 2 partials -> split-bf16 ctx
//   out_gemm2  : 128x64 split-bf16 MFMA, same corrected schedule -> fp32
// Workspace peak 61MB (aliased dead regions).
// ---------------------------------------------------------------------------

typedef __attribute__((ext_vector_type(8)))  short short8;
typedef __attribute__((ext_vector_type(4)))  short short4v;
typedef __attribute__((ext_vector_type(8)))  float float8;
typedef __attribute__((ext_vector_type(4)))  float f32x4;
typedef __attribute__((ext_vector_type(16))) float f32x16;
typedef __attribute__((ext_vector_type(4)))  int   int4v;

#define D_MODEL 1024
#define NHEAD   16
#define HD      64
#define SEQ     2048
#define N3      (3*D_MODEL)
#define MB      (1024*1024)

static __device__ __forceinline__ float bf2f(short s) {
    unsigned u = ((unsigned)(unsigned short)s) << 16;
    return __builtin_bit_cast(float, u);
}
static __device__ __forceinline__ short f2bf(float f) {
    unsigned u = __builtin_bit_cast(unsigned, f);
    u = (u + 0x7fff + ((u >> 16) & 1)) >> 16;   // RNE
    return (short)u;
}
// hardware packed f32->bf16 (RNE), 1 instr
static __device__ __forceinline__ unsigned cvtpk(float a, float b) {
    unsigned r;
    asm("v_cvt_pk_bf16_f32 %0, %1, %2" : "=v"(r) : "v"(a), "v"(b));
    return r;
}
// in-place cross-half swap: a[32..63] <-> b[0..31]
#define PLSWAP(a, b) asm("v_permlane32_swap_b32 %0, %1" : "+v"(a), "+v"(b))

static __device__ __forceinline__ void gl16(const short* g, short* l) {
    __builtin_amdgcn_global_load_lds(
        (const __attribute__((address_space(1))) unsigned int*)g,
        (__attribute__((address_space(3))) unsigned int*)l, 16, 0, 0);
}

// ---------------------------------------------------------------------------
// prep: blocks [0,2048) split x; [2048,5120) transpose-split Wqkv;
//       [5120,6144) transpose-split Wout.
// ---------------------------------------------------------------------------
__global__ __launch_bounds__(256) void prep(
    const float* __restrict__ x, const float* __restrict__ Wqkv,
    const float* __restrict__ Wout,
    short* __restrict__ Xh, short* __restrict__ Xl,
    short* __restrict__ Wh, short* __restrict__ Wl,
    short* __restrict__ Woh, short* __restrict__ Wol)
{
    __shared__ float tile[32][33];
    const int bid = blockIdx.x;
    const int tid = threadIdx.x;

    if (bid < 2048) {                        // ---- split x ----
        const int i = (bid * 256 + tid) * 8;
        const float8 v = *(const float8*)&x[i];
        short8 h, l;
#pragma unroll
        for (int j = 0; j < 8; ++j) {
            h[j] = f2bf(v[j]);
            l[j] = f2bf(v[j] - bf2f(h[j]));
        }
        *(short8*)&Xh[i] = h;
        *(short8*)&Xl[i] = l;
        return;
    }

    // ---- transpose + split a weight matrix ----
    const float* in; short *hi, *lo; int K, N, bx, by;
    if (bid < 5120) {
        const int b2 = bid - 2048;
        in = Wqkv; hi = Wh; lo = Wl; K = D_MODEL; N = N3;
        bx = b2 % 96; by = b2 / 96;
    } else {
        const int b3 = bid - 5120;
        in = Wout; hi = Woh; lo = Wol; K = D_MODEL; N = D_MODEL;
        bx = b3 & 31; by = b3 >> 5;
    }
    const int n0 = bx * 32, k0 = by * 32;
    const int tx = tid & 31, ty = tid >> 5;
#pragma unroll
    for (int i = 0; i < 4; ++i)
        tile[ty + 8*i][tx] = in[(k0 + ty + 8*i) * N + (n0 + tx)];
    __syncthreads();
#pragma unroll
    for (int i = 0; i < 4; ++i) {
        const float v  = tile[tx][ty + 8*i];
        const short vh = f2bf(v);
        const short vl = f2bf(v - bf2f(vh));
        const int idx  = (n0 + ty + 8*i) * K + (k0 + tx);
        hi[idx] = vh;
        lo[idx] = vl;
    }
}

// ---------------------------------------------------------------------------
// QKV GEMM. BM=128 BN=192 BK=32, 512 threads (8 waves 2Mx4N), per-wave
// output 64x48. LDS: 2 x 40KB buffers -> 2 blocks/CU. Corrected counted-vmcnt
// schedule per tile:
//   barrier A  (all waves done reading other buffer -> safe to stage it)
//   stage(t+1) (writes just-released buffer)
//   vmcnt(5)   (own stage(t) done; stage(t+1)'s 5 loads stay in flight)
//   barrier B  (ALL waves' stage(t) done -> buffer certified)   <- R9's miss
//   14 ds_read -> lgkmcnt(0) -> 36 MFMA
// No vmcnt(0) drain in the main loop; prefetch window = full tile.
// ---------------------------------------------------------------------------
#define QBUF_SH 20480          // shorts per LDS buffer (40KB)
#define OFF_AL  4096
#define OFF_BH  8192
#define OFF_BL  14336

__global__ __launch_bounds__(512, 4) void qkv_gemm8(
    const short* __restrict__ Xh, const short* __restrict__ Xl,
    const short* __restrict__ Bh, const short* __restrict__ Bl,
    const float* __restrict__ bias,
    short* __restrict__ Qo, short* __restrict__ Ko, short* __restrict__ Vt)
{
    __shared__ __attribute__((aligned(16))) short smem[2 * QBUF_SH];

    const int tid  = threadIdx.x;
    const int wave = tid >> 6, lane = tid & 63;
    const int q4 = lane >> 4, l16 = lane & 15;
    const int wr = wave >> 2, wc = wave & 3;
    const int csw = (q4 ^ ((l16 ^ (l16 >> 2)) & 3)) * 8;

    const int flat = blockIdx.x;
    const int sw = (flat & 7) * 64 + (flat >> 3);
    const int mt = sw & 31, nt = sw >> 5;
    const int m0 = mt * 128, n0 = nt * 192;

    // staging map: 2560 chunks = [Ah 512][Al 512][Bh 768][Bl 768], 5/thread
    const short* srcp[5];
#pragma unroll
    for (int j = 0; j < 5; ++j) {
        const int id = j * 512 + tid;
        int r; const short* mat; int row0;
        if (id < 512)       { r = id >> 2;          mat = Xh; row0 = m0; }
        else if (id < 1024) { r = (id - 512) >> 2;  mat = Xl; row0 = m0; }
        else if (id < 1792) { r = (id - 1024) >> 2; mat = Bh; row0 = n0; }
        else                { r = (id - 1792) >> 2; mat = Bl; row0 = n0; }
        const int cg = (id & 3) ^ ((r ^ (r >> 2)) & 3);
        srcp[j] = &mat[(size_t)(row0 + r) * D_MODEL + cg * 8];
    }

    auto stage = [&](int b) {
#pragma unroll
        for (int j = 0; j < 5; ++j) {
            gl16(srcp[j], smem + b * QBUF_SH + (j * 512 + tid) * 8);
            srcp[j] += 32;                  // advance one K-tile
        }
    };

    f32x4 acc[4][3];
#pragma unroll
    for (int i = 0; i < 4; ++i)
#pragma unroll
        for (int j = 0; j < 3; ++j) acc[i][j] = (f32x4){0.f, 0.f, 0.f, 0.f};

    stage(0);                               // tile 0 in flight

    for (int t = 0; t < 32; ++t) {
        const short* base = smem + (t & 1) * QBUF_SH;
        const short* Ah_s = base;
        const short* Al_s = base + OFF_AL;
        const short* Bh_s = base + OFF_BH;
        const short* Bl_s = base + OFF_BL;

        // barrier A: all waves finished READING the other buffer
        __builtin_amdgcn_s_barrier();
        if (t < 31) {
            stage((t + 1) & 1);             // write the just-released buffer
            // own stage(t) loads complete; stage(t+1)'s 5 remain in flight
            asm volatile("s_waitcnt vmcnt(5)" ::: "memory");
        } else {
            asm volatile("s_waitcnt vmcnt(0)" ::: "memory");
        }
        // barrier B: ALL waves' stage(t) complete -> buffer certified
        __builtin_amdgcn_s_barrier();
        __builtin_amdgcn_sched_barrier(0);

        // all 14 fragment ds_reads for this tile
        short8 bhf[3], blf[3], ahf[4], alf[4];
#pragma unroll
        for (int n = 0; n < 3; ++n) {
            const int rb = (wc * 48 + n * 16 + l16) * 32 + csw;
            bhf[n] = *(const short8*)(Bh_s + rb);
            blf[n] = *(const short8*)(Bl_s + rb);
        }
#pragma unroll
        for (int ti = 0; ti < 4; ++ti) {
            const int ra = (wr * 64 + ti * 16 + l16) * 32 + csw;
            ahf[ti] = *(const short8*)(Ah_s + ra);
            alf[ti] = *(const short8*)(Al_s + ra);
        }
        asm volatile("s_waitcnt lgkmcnt(0)" ::: "memory");
        __builtin_amdgcn_sched_barrier(0);
        __builtin_amdgcn_s_setprio(1);
#pragma unroll
        for (int ti = 0; ti < 4; ++ti)
#pragma unroll
            for (int n = 0; n < 3; ++n) {
                acc[ti][n] = __builtin_amdgcn_mfma_f32_16x16x32_bf16(ahf[ti], bhf[n], acc[ti][n], 0, 0, 0);
                acc[ti][n] = __builtin_amdgcn_mfma_f32_16x16x32_bf16(ahf[ti], blf[n], acc[ti][n], 0, 0, 0);
                acc[ti][n] = __builtin_amdgcn_mfma_f32_16x16x32_bf16(alf[ti], bhf[n], acc[ti][n], 0, 0, 0);
            }
        __builtin_amdgcn_s_setprio(0);
    }

    // epilogue: scatter Q (pre-scaled), K, Vt
    const float SCALE_Q = 0.125f * 1.4426950408889634f;
#pragma unroll
    for (int tj = 0; tj < 3; ++tj) {
        const int jj = wc * 48 + tj * 16 + l16;   // 0..191 within head
        const int n  = nt * 192 + jj;
        const float bv = bias[n];
#pragma unroll
        for (int ti = 0; ti < 4; ++ti) {
            const int mb = m0 + wr * 64 + ti * 16 + q4 * 4;
            const int b = mb >> 11;
            const int s = mb & 2047;
            const int bh_ = b * NHEAD + nt;
            if (jj >= 128) {                      // Vt: s is fast axis -> short4
                short4v v4;
#pragma unroll
                for (int r = 0; r < 4; ++r) v4[r] = f2bf(acc[ti][tj][r] + bv);
                *(short4v*)&Vt[(bh_ * HD + (jj - 128)) * SEQ + s] = v4;
            } else if (jj < 64) {
#pragma unroll
                for (int r = 0; r < 4; ++r)
                    Qo[(bh_ * SEQ + s + r) * HD + jj] = f2bf((acc[ti][tj][r] + bv) * SCALE_Q);
            } else {
#pragma unroll
                for (int r = 0; r < 4; ++r)
                    Ko[(bh_ * SEQ + s + r) * HD + (jj - 64)] = f2bf(acc[ti][tj][r] + bv);
            }
        }
    }
}

// ---------------------------------------------------------------------------
// Transposed-score flash attention, KV-SPLIT x2. Grid (32 bh, 16 qb, 2 kvz).
// VALU cuts: scores arrive pre-shifted (C = -m seed, mseed kept live);
// defer-max on RELATIVE threshold (m init 0); l via ones-row MFMA.
// ---------------------------------------------------------------------------
__global__ __launch_bounds__(256, 2) void attn_tscore(
    const short* __restrict__ Q, const short* __restrict__ K,
    const short* __restrict__ Vt,
    float* __restrict__ Opart, float2* __restrict__ Ml)
{
    __shared__ __attribute__((aligned(16))) char smem[36864];
    short (*Ks)[72] = (short(*)[72])smem;                 // [2*64 key][64 d + pad]
    short (*Vs)[72] = (short(*)[72])(smem + 18432);       // [2*64 d][64 key + pad]

    const int bh  = blockIdx.x;               // 0..31
    const int qb  = blockIdx.y;               // 0..15
    const int kvz = blockIdx.z;               // 0..1

    const short* Qp  = Q  + (size_t)bh * SEQ * HD;
    const short* Kp  = K  + (size_t)bh * SEQ * HD + (size_t)kvz * 1024 * HD;
    const short* Vtp = Vt + (size_t)bh * HD * SEQ + (size_t)kvz * 1024;

    const int tid  = threadIdx.x;
    const int wave = tid >> 6, lane = tid & 63;
    const int l5 = lane & 31, hf = lane >> 5;
    const int q0w = qb * 128 + wave * 32;

    short8 qf[4];
#pragma unroll
    for (int c = 0; c < 4; ++c)
        qf[c] = *(const short8*)&Qp[(q0w + l5) * HD + c * 16 + hf * 8];

    short8 one8;
#pragma unroll
    for (int i = 0; i < 8; ++i) one8[i] = (short)0x3F80;  // bf16 1.0

    f32x16 oacc0 = (f32x16)(0.f), oacc1 = (f32x16)(0.f);
    f32x16 lacc  = (f32x16)(0.f);             // all rows = running sum of P
    f32x16 mseed = (f32x16)(0.f);             // splat(-m), live across iters
    float m = 0.f;                            // running max (finite init!)

    // staging: 256 threads cover 64 rows x 64 cols (2x short8 each for K and V)
    const int sr = tid >> 2;          // 0..63
    const int sc = (tid & 3) * 16;    // 0,16,32,48

    short8 kr0 = *(const short8*)&Kp[sr * HD + sc];
    short8 kr1 = *(const short8*)&Kp[sr * HD + sc + 8];
    short8 vr0 = *(const short8*)&Vtp[sr * SEQ + sc];
    short8 vr1 = *(const short8*)&Vtp[sr * SEQ + sc + 8];
    *(short8*)&Ks[sr][sc]     = kr0;
    *(short8*)&Ks[sr][sc + 8] = kr1;
    *(short8*)&Vs[sr][sc]     = vr0;
    *(short8*)&Vs[sr][sc + 8] = vr1;
    __syncthreads();

    for (int kc = 0; kc < 16; ++kc) {
        const int buf = (kc & 1) << 6;

        // issue next tile's global loads (hidden under this tile's compute)
        if (kc < 15) {
            const int nkb = (kc + 1) << 6;
            kr0 = *(const short8*)&Kp[(nkb + sr) * HD + sc];
            kr1 = *(const short8*)&Kp[(nkb + sr) * HD + sc + 8];
            vr0 = *(const short8*)&Vtp[sr * SEQ + nkb + sc];
            vr1 = *(const short8*)&Vtp[sr * SEQ + nkb + sc + 8];
        }

        // ---- scores (pre-shifted by -m via C-seed): two 32-key tiles ----
        f32x16 s0, s1;
        {
            const short8 ka0 = *(const short8*)&Ks[buf + l5][hf * 8];
            const short8 ka1 = *(const short8*)&Ks[buf + 32 + l5][hf * 8];
            s0 = __builtin_amdgcn_mfma_f32_32x32x16_bf16(ka0, qf[0], mseed, 0, 0, 0);
            s1 = __builtin_amdgcn_mfma_f32_32x32x16_bf16(ka1, qf[0], mseed, 0, 0, 0);
        }
#pragma unroll
        for (int c = 1; c < 4; ++c) {
            const short8 ka0 = *(const short8*)&Ks[buf + l5][c * 16 + hf * 8];
            const short8 ka1 = *(const short8*)&Ks[buf + 32 + l5][c * 16 + hf * 8];
            s0 = __builtin_amdgcn_mfma_f32_32x32x16_bf16(ka0, qf[c], s0, 0, 0, 0);
            s1 = __builtin_amdgcn_mfma_f32_32x32x16_bf16(ka1, qf[c], s1, 0, 0, 0);
        }

        // ---- relative row max over 32 scores/lane (+ cross-half) ----
        float t[8];
#pragma unroll
        for (int i = 0; i < 8; ++i)
            t[i] = fmaxf(fmaxf(s0[i], s0[i + 8]), fmaxf(s1[i], s1[i + 8]));
        float pmax = fmaxf(fmaxf(fmaxf(t[0], t[1]), fmaxf(t[2], t[3])),
                           fmaxf(fmaxf(t[4], t[5]), fmaxf(t[6], t[7])));
        pmax = fmaxf(pmax, __shfl_xor(pmax, 32, 64));

        // ---- defer-max (T13, relative): rescale only past threshold ----
        if (!__all(pmax <= 8.0f)) {
            const float delta = fmaxf(pmax, 0.0f);
            const float alpha = exp2f(-delta);
#pragma unroll
            for (int i = 0; i < 16; ++i) {
                oacc0[i] *= alpha; oacc1[i] *= alpha; lacc[i] *= alpha;
            }
            m += delta;
#pragma unroll
            for (int i = 0; i < 16; ++i) mseed[i] = -m;
#pragma unroll
            for (int i = 0; i < 16; ++i) { s0[i] -= delta; s1[i] -= delta; }
        }

        // ---- P = exp2(s_rel) (no subs on common path) ----
        float p0[16], p1[16];
#pragma unroll
        for (int i = 0; i < 16; ++i) { p0[i] = exp2f(s0[i]); p1[i] = exp2f(s1[i]); }

        // ---- pack P -> 4 bf16 B-fragments (cvt_pk + permlane32_swap) ----
        unsigned u0 = cvtpk(p0[0],  p0[1]),  u1 = cvtpk(p0[2],  p0[3]);
        unsigned u2 = cvtpk(p0[4],  p0[5]),  u3 = cvtpk(p0[6],  p0[7]);
        unsigned u4 = cvtpk(p0[8],  p0[9]),  u5 = cvtpk(p0[10], p0[11]);
        unsigned u6 = cvtpk(p0[12], p0[13]), u7 = cvtpk(p0[14], p0[15]);
        unsigned w0 = cvtpk(p1[0],  p1[1]),  w1 = cvtpk(p1[2],  p1[3]);
        unsigned w2 = cvtpk(p1[4],  p1[5]),  w3 = cvtpk(p1[6],  p1[7]);
        unsigned w4 = cvtpk(p1[8],  p1[9]),  w5 = cvtpk(p1[10], p1[11]);
        unsigned w6 = cvtpk(p1[12], p1[13]), w7 = cvtpk(p1[14], p1[15]);
        PLSWAP(u0, u2); PLSWAP(u1, u3); PLSWAP(u4, u6); PLSWAP(u5, u7);
        PLSWAP(w0, w2); PLSWAP(w1, w3); PLSWAP(w4, w6); PLSWAP(w5, w7);
        int4v pb0 = (int4v){ (int)u0, (int)u1, (int)u2, (int)u3 };
        int4v pb1 = (int4v){ (int)u4, (int)u5, (int)u6, (int)u7 };
        int4v pb2 = (int4v){ (int)w0, (int)w1, (int)w2, (int)w3 };
        int4v pb3 = (int4v){ (int)w4, (int)w5, (int)w6, (int)w7 };
        const short8 pbf0 = __builtin_bit_cast(short8, pb0);
        const short8 pbf1 = __builtin_bit_cast(short8, pb1);
        const short8 pbf2 = __builtin_bit_cast(short8, pb2);
        const short8 pbf3 = __builtin_bit_cast(short8, pb3);

        // ---- PV: O += V[d][k-slice] . P ; l-row via ones MFMA ----
        {
            const short8 va0 = *(const short8*)&Vs[buf + l5][hf * 8];
            const short8 va1 = *(const short8*)&Vs[buf + l5][16 + hf * 8];
            const short8 va2 = *(const short8*)&Vs[buf + l5][32 + hf * 8];
            const short8 va3 = *(const short8*)&Vs[buf + l5][48 + hf * 8];
            oacc0 = __builtin_amdgcn_mfma_f32_32x32x16_bf16(va0, pbf0, oacc0, 0, 0, 0);
            oacc0 = __builtin_amdgcn_mfma_f32_32x32x16_bf16(va1, pbf1, oacc0, 0, 0, 0);
            oacc0 = __builtin_amdgcn_mfma_f32_32x32x16_bf16(va2, pbf2, oacc0, 0, 0, 0);
            oacc0 = __builtin_amdgcn_mfma_f32_32x32x16_bf16(va3, pbf3, oacc0, 0, 0, 0);
            const short8 vb0 = *(const short8*)&Vs[buf + 32 + l5][hf * 8];
            const short8 vb1 = *(const short8*)&Vs[buf + 32 + l5][16 + hf * 8];
            const short8 vb2 = *(const short8*)&Vs[buf + 32 + l5][32 + hf * 8];
            const short8 vb3 = *(const short8*)&Vs[buf + 32 + l5][48 + hf * 8];
            oacc1 = __builtin_amdgcn_mfma_f32_32x32x16_bf16(vb0, pbf0, oacc1, 0, 0, 0);
            oacc1 = __builtin_amdgcn_mfma_f32_32x32x16_bf16(vb1, pbf1, oacc1, 0, 0, 0);
            oacc1 = __builtin_amdgcn_mfma_f32_32x32x16_bf16(vb2, pbf2, oacc1, 0, 0, 0);
            oacc1 = __builtin_amdgcn_mfma_f32_32x32x16_bf16(vb3, pbf3, oacc1, 0, 0, 0);
            lacc  = __builtin_amdgcn_mfma_f32_32x32x16_bf16(one8, pbf0, lacc, 0, 0, 0);
            lacc  = __builtin_amdgcn_mfma_f32_32x32x16_bf16(one8, pbf1, lacc, 0, 0, 0);
            lacc  = __builtin_amdgcn_mfma_f32_32x32x16_bf16(one8, pbf2, lacc, 0, 0, 0);
            lacc  = __builtin_amdgcn_mfma_f32_32x32x16_bf16(one8, pbf3, lacc, 0, 0, 0);
        }

        // ---- write next tile into other buffer; one barrier per iter ----
        if (kc < 15) {
            const int wb = ((kc + 1) & 1) << 6;
            *(short8*)&Ks[wb + sr][sc]     = kr0;
            *(short8*)&Ks[wb + sr][sc + 8] = kr1;
            *(short8*)&Vs[wb + sr][sc]     = vr0;
            *(short8*)&Vs[wb + sr][sc + 8] = vr1;
        }
        __syncthreads();
    }

    // ---- partial epilogue: raw unnormalized O (MFMA layout) + (m,l) ----
    float* Op = Opart + ((((size_t)kvz * 32 + bh) * 16 + qb) * 4 + wave) * 2048;
#pragma unroll
    for (int r = 0; r < 4; ++r) {
        float4 v;
        v.x = oacc0[4*r]; v.y = oacc0[4*r+1]; v.z = oacc0[4*r+2]; v.w = oacc0[4*r+3];
        *(float4*)&Op[r * 256 + lane * 4] = v;
    }
#pragma unroll
    for (int r = 0; r < 4; ++r) {
        float4 v;
        v.x = oacc1[4*r]; v.y = oacc1[4*r+1]; v.z = oacc1[4*r+2]; v.w = oacc1[4*r+3];
        *(float4*)&Op[(4 + r) * 256 + lane * 4] = v;
    }
    if (hf == 0) {
        float2 mv; mv.x = m; mv.y = lacc[0];
        Ml[((size_t)kvz * 32 + bh) * 2048 + q0w + l5] = mv;
    }
}

// ---------------------------------------------------------------------------
// LSE-merge of the 2 KV partials -> split-bf16 ctx. One wave per 32-q group.
// ---------------------------------------------------------------------------
__global__ __launch_bounds__(256) void attn_merge(
    const float* __restrict__ Opart, const float2* __restrict__ Ml,
    short* __restrict__ Ch, short* __restrict__ Cl)
{
    __shared__ float epi[4][32][68];          // 34.8 KB
    const int tid = threadIdx.x, wave = tid >> 6, lane = tid & 63;
    const int l5 = lane & 31, hf = lane >> 5;
    const int task = blockIdx.x * 4 + wave;   // 0..2047
    const int bh = task >> 6;
    const int qb = (task >> 2) & 15;
    const int wq = task & 3;
    const int bi = bh >> 4, hi_ = bh & 15;
    const int q0w = qb * 128 + wq * 32;

    const float2 v0 = Ml[(size_t)bh * 2048 + q0w + l5];
    const float2 v1 = Ml[((size_t)32 + bh) * 2048 + q0w + l5];
    const float M  = fmaxf(v0.x, v1.x);
    const float w0 = exp2f(v0.x - M), w1 = exp2f(v1.x - M);
    const float inv = 1.0f / (v0.y * w0 + v1.y * w1);
    const float f0 = w0 * inv, f1 = w1 * inv;

    const float* Op0 = Opart + (((size_t)bh * 16 + qb) * 4 + wq) * 2048;
    const float* Op1 = Opart + ((((size_t)32 + bh) * 16 + qb) * 4 + wq) * 2048;
    float o[32];
#pragma unroll
    for (int r = 0; r < 8; ++r) {
        const float4 a = *(const float4*)&Op0[r * 256 + lane * 4];
        const float4 b = *(const float4*)&Op1[r * 256 + lane * 4];
        o[4*r]   = a.x * f0 + b.x * f1;
        o[4*r+1] = a.y * f0 + b.y * f1;
        o[4*r+2] = a.z * f0 + b.z * f1;
        o[4*r+3] = a.w * f0 + b.w * f1;
    }
#pragma unroll
    for (int r = 0; r < 16; ++r) {
        const int d = (r & 3) + 8 * (r >> 2) + 4 * hf;
        epi[wave][l5][d]      = o[r];
        epi[wave][l5][32 + d] = o[16 + r];
    }
    __builtin_amdgcn_s_waitcnt(0);
#pragma unroll
    for (int pass = 0; pass < 8; ++pass) {
        const int row = pass * 4 + (lane >> 4);
        const int col = (lane & 15) * 4;
        const float4 v = *(const float4*)&epi[wave][row][col];
        const float ov[4] = {v.x, v.y, v.z, v.w};
        short4v hh, ll;
#pragma unroll
        for (int i = 0; i < 4; ++i) {
            hh[i] = f2bf(ov[i]);
            ll[i] = f2bf(ov[i] - bf2f(hh[i]));
        }
        const size_t co = ((size_t)(bi * SEQ + q0w + row)) * D_MODEL + hi_ * HD + col;
        *(short4v*)&Ch[co] = hh;
        *(short4v*)&Cl[co] = ll;
    }
}

// ---------------------------------------------------------------------------
// Output GEMM v2: BM=128 BN=64 BK=32, 256 threads (4 waves 2Mx2N), per-wave
// 64x32. Corrected counted-vmcnt schedule (vmcnt(6) BEFORE certify barrier),
// 2x24KB LDS, grid 512. fp32 out.
// ---------------------------------------------------------------------------
#define OBUF_SH 12288          // shorts per LDS buffer (24KB)
#define OO_AL   4096
#define OO_BH   8192
#define OO_BL   10240

__global__ __launch_bounds__(256, 4) void out_gemm2(
    const short* __restrict__ Ah, const short* __restrict__ Al,
    const short* __restrict__ Bh, const short* __restrict__ Bl,
    const float* __restrict__ bias, float* __restrict__ out)
{
    __shared__ __attribute__((aligned(16))) short smem[2 * OBUF_SH];

    const int tid  = threadIdx.x;
    const int wave = tid >> 6, lane = tid & 63;
    const int q4 = lane >> 4, l16 = lane & 15;
    const int wr = wave >> 1, wc = wave & 1;
    const int csw = (q4 ^ ((l16 ^ (l16 >> 2)) & 3)) * 8;

    const int flat = blockIdx.x;
    const int sw = (flat & 7) * 64 + (flat >> 3);
    const int mt = sw & 31, nt = sw >> 5;
    const int m0 = mt * 128, n0 = nt * 64;

    // staging map: 1536 chunks = [Ah 512][Al 512][Bh 256][Bl 256], 6/thread
    const short* srcp[6];
#pragma unroll
    for (int j = 0; j < 6; ++j) {
        const int id = j * 256 + tid;
        int r; const short* mat; int row0;
        if (id < 512)       { r = id >> 2;          mat = Ah; row0 = m0; }
        else if (id < 1024) { r = (id - 512) >> 2;  mat = Al; row0 = m0; }
        else if (id < 1280) { r = (id - 1024) >> 2; mat = Bh; row0 = n0; }
        else                { r = (id - 1280) >> 2; mat = Bl; row0 = n0; }
        const int cg = (id & 3) ^ ((r ^ (r >> 2)) & 3);
        srcp[j] = &mat[(size_t)(row0 + r) * D_MODEL + cg * 8];
    }

    auto stage = [&](int b) {
#pragma unroll
        for (int j = 0; j < 6; ++j) {
            gl16(srcp[j], smem + b * OBUF_SH + (j * 256 + tid) * 8);
            srcp[j] += 32;                  // advance one K-tile
        }
    };

    f32x4 acc[4][2];
#pragma unroll
    for (int i = 0; i < 4; ++i)
#pragma unroll
        for (int j = 0; j < 2; ++j) acc[i][j] = (f32x4){0.f, 0.f, 0.f, 0.f};

    stage(0);

    for (int t = 0; t < 32; ++t) {
        const short* base = smem + (t & 1) * OBUF_SH;
        const short* Ah_s = base;
        const short* Al_s = base + OO_AL;
        const short* Bh_s = base + OO_BH;
        const short* Bl_s = base + OO_BL;

        // barrier A: all waves finished READING the other buffer
        __builtin_amdgcn_s_barrier();
        if (t < 31) {
            stage((t + 1) & 1);
            asm volatile("s_waitcnt vmcnt(6)" ::: "memory");
        } else {
            asm volatile("s_waitcnt vmcnt(0)" ::: "memory");
        }
        // barrier B: ALL waves' stage(t) complete
        __builtin_amdgcn_s_barrier();
        __builtin_amdgcn_sched_barrier(0);

        short8 bhf[2], blf[2], ahf[4], alf[4];
#pragma unroll
        for (int n = 0; n < 2; ++n) {
            const int rb = (wc * 32 + n * 16 + l16) * 32 + csw;
            bhf[n] = *(const short8*)(Bh_s + rb);
            blf[n] = *(const short8*)(Bl_s + rb);
        }
#pragma unroll
        for (int ti = 0; ti < 4; ++ti) {
            const int ra = (wr * 64 + ti * 16 + l16) * 32 + csw;
            ahf[ti] = *(const short8*)(Ah_s + ra);
            alf[ti] = *(const short8*)(Al_s + ra);
        }
        asm volatile("s_waitcnt lgkmcnt(0)" ::: "memory");
        __builtin_amdgcn_sched_barrier(0);
        __builtin_amdgcn_s_setprio(1);
#pragma unroll
        for (int ti = 0; ti < 4; ++ti)
#pragma unroll
            for (int n = 0; n < 2; ++n) {
                acc[ti][n] = __builtin_amdgcn_mfma_f32_16x16x32_bf16(ahf[ti], bhf[n], acc[ti][n], 0, 0, 0);
                acc[ti][n] = __builtin_amdgcn_mfma_f32_16x16x32_bf16(ahf[ti], blf[n], acc[ti][n], 0, 0, 0);
                acc[ti][n] = __builtin_amdgcn_mfma_f32_16x16x32_bf16(alf[ti], bhf[n], acc[ti][n], 0, 0, 0);
            }
        __builtin_amdgcn_s_setprio(0);
    }

#pragma unroll
    for (int tj = 0; tj < 2; ++tj) {
        const int n = n0 + wc * 32 + tj * 16 + l16;
        const float bv = bias[n];
#pragma unroll
        for (int ti = 0; ti < 4; ++ti) {
            const int mb = m0 + wr * 64 + ti * 16 + q4 * 4;
#pragma unroll
            for (int r = 0; r < 4; ++r)
                out[(size_t)(mb + r) * D_MODEL + n] = acc[ti][tj][r] + bv;
        }
    }
}

// ---------------------------------------------------------------------------
// Workspace layout (peak 61MB, aliasing dead regions):
//   0- 2 Woh | 2- 4 Wol | 4-12 Qb (then Ch) | 12-20 Kb (then Cl) | 20-28 Vtb
//   28-60 Opart (before attn: 28-36 Xh, 36-44 Xl, 44-50 Wh, 50-56 Wl)
//   60-61 Ml
// ---------------------------------------------------------------------------
extern "C" void kernel_launch(void* const* d_in, const int* in_sizes, int n_in,
                              void* d_out, int out_size, void* d_ws, size_t ws_size,
                              hipStream_t stream)
{
    const float* x    = (const float*)d_in[0];
    const float* Wqkv = (const float*)d_in[1];
    const float* bqkv = (const float*)d_in[2];
    const float* Wout = (const float*)d_in[3];
    const float* bout = (const float*)d_in[4];
    float* out = (float*)d_out;

    char* ws = (char*)d_ws;
    short*  Woh   = (short*)(ws);             //  2 MB Wout^T hi
    short*  Wol   = (short*)(ws +  2*MB);     //  2 MB Wout^T lo
    short*  Qb    = (short*)(ws +  4*MB);     //  8 MB [32][2048][64] (pre-scaled)
    short*  Kb    = (short*)(ws + 12*MB);     //  8 MB
    short*  Vtb   = (short*)(ws + 20*MB);     //  8 MB [32][64][2048]
    float*  Opart = (float*)(ws + 28*MB);     // 32 MB [2][32][16][4][2048]
    float2* Ml    = (float2*)(ws + 60*MB);    //  1 MB [2][32][2048]
    short*  Ch    = (short*)(ws +  4*MB);     //  8 MB ctx hi  (aliases Qb)
    short*  Cl    = (short*)(ws + 12*MB);     //  8 MB ctx lo  (aliases Kb)
    short*  Xh    = (short*)(ws + 28*MB);     //  8 MB x hi    (aliases Opart)
    short*  Xl    = (short*)(ws + 36*MB);     //  8 MB x lo
    short*  Wh    = (short*)(ws + 44*MB);     //  6 MB Wqkv^T hi
    short*  Wl    = (short*)(ws + 50*MB);     //  6 MB Wqkv^T lo

    prep<<<6144, 256, 0, stream>>>(x, Wqkv, Wout, Xh, Xl, Wh, Wl, Woh, Wol);
    qkv_gemm8<<<dim3(512), 512, 0, stream>>>(Xh, Xl, Wh, Wl, bqkv, Qb, Kb, Vtb);
    attn_tscore<<<dim3(32, 16, 2), 256, 0, stream>>>(Qb, Kb, Vtb, Opart, Ml);
    attn_merge<<<512, 256, 0, stream>>>(Opart, Ml, Ch, Cl);
    out_gemm2<<<dim3(512), 256, 0, stream>>>(Ch, Cl, Woh, Wol, bout, out);
}

// Round 13
// 258.969 us; speedup vs baseline: 1.0427x; 1.0202x over previous
//
#include <hip/hip_runtime.h>

// ---------------------------------------------------------------------------
// MultiHeadAttention, fp32 in/out. 5-kernel pipeline (best-of-each-round):
//   prep       : Wqkv^T/Wout^T transpose+split-bf16, x split-bf16 (fused)
//   qkv_gemm8  : 128x192 split-bf16 MFMA, counted-vmcnt + certify barrier
//                (R11, 74.2us), 2x40KB LDS -> 2 blocks/CU
//   attn_tscore: R8-measured variant (67.2us): transposed-score flash,
//                KVBLK=64, KV-SPLIT x2, abs-thresh defer-max, VALU row-sum
//   attn_merge : LSE-merge of 2 partials -> split-bf16 ctx
//   out_gemm2  : 128x64 split-bf16 MFMA, counted-vmcnt + certify -> fp32
// Workspace peak 61MB (aliased dead regions).
// (R12 bench was an infra failure; identical source resubmitted.)
// ---------------------------------------------------------------------------

typedef __attribute__((ext_vector_type(8)))  short short8;
typedef __attribute__((ext_vector_type(4)))  short short4v;
typedef __attribute__((ext_vector_type(8)))  float float8;
typedef __attribute__((ext_vector_type(4)))  float f32x4;
typedef __attribute__((ext_vector_type(16))) float f32x16;
typedef __attribute__((ext_vector_type(4)))  int   int4v;

#define D_MODEL 1024
#define NHEAD   16
#define HD      64
#define SEQ     2048
#define N3      (3*D_MODEL)
#define MB      (1024*1024)

static __device__ __forceinline__ float bf2f(short s) {
    unsigned u = ((unsigned)(unsigned short)s) << 16;
    return __builtin_bit_cast(float, u);
}
static __device__ __forceinline__ short f2bf(float f) {
    unsigned u = __builtin_bit_cast(unsigned, f);
    u = (u + 0x7fff + ((u >> 16) & 1)) >> 16;   // RNE
    return (short)u;
}
// hardware packed f32->bf16 (RNE), 1 instr
static __device__ __forceinline__ unsigned cvtpk(float a, float b) {
    unsigned r;
    asm("v_cvt_pk_bf16_f32 %0, %1, %2" : "=v"(r) : "v"(a), "v"(b));
    return r;
}
// in-place cross-half swap: a[32..63] <-> b[0..31]
#define PLSWAP(a, b) asm("v_permlane32_swap_b32 %0, %1" : "+v"(a), "+v"(b))

static __device__ __forceinline__ void gl16(const short* g, short* l) {
    __builtin_amdgcn_global_load_lds(
        (const __attribute__((address_space(1))) unsigned int*)g,
        (__attribute__((address_space(3))) unsigned int*)l, 16, 0, 0);
}

// ---------------------------------------------------------------------------
// prep: blocks [0,2048) split x; [2048,5120) transpose-split Wqkv;
//       [5120,6144) transpose-split Wout.
// ---------------------------------------------------------------------------
__global__ __launch_bounds__(256) void prep(
    const float* __restrict__ x, const float* __restrict__ Wqkv,
    const float* __restrict__ Wout,
    short* __restrict__ Xh, short* __restrict__ Xl,
    short* __restrict__ Wh, short* __restrict__ Wl,
    short* __restrict__ Woh, short* __restrict__ Wol)
{
    __shared__ float tile[32][33];
    const int bid = blockIdx.x;
    const int tid = threadIdx.x;

    if (bid < 2048) {                        // ---- split x ----
        const int i = (bid * 256 + tid) * 8;
        const float8 v = *(const float8*)&x[i];
        short8 h, l;
#pragma unroll
        for (int j = 0; j < 8; ++j) {
            h[j] = f2bf(v[j]);
            l[j] = f2bf(v[j] - bf2f(h[j]));
        }
        *(short8*)&Xh[i] = h;
        *(short8*)&Xl[i] = l;
        return;
    }

    // ---- transpose + split a weight matrix ----
    const float* in; short *hi, *lo; int K, N, bx, by;
    if (bid < 5120) {
        const int b2 = bid - 2048;
        in = Wqkv; hi = Wh; lo = Wl; K = D_MODEL; N = N3;
        bx = b2 % 96; by = b2 / 96;
    } else {
        const int b3 = bid - 5120;
        in = Wout; hi = Woh; lo = Wol; K = D_MODEL; N = D_MODEL;
        bx = b3 & 31; by = b3 >> 5;
    }
    const int n0 = bx * 32, k0 = by * 32;
    const int tx = tid & 31, ty = tid >> 5;
#pragma unroll
    for (int i = 0; i < 4; ++i)
        tile[ty + 8*i][tx] = in[(k0 + ty + 8*i) * N + (n0 + tx)];
    __syncthreads();
#pragma unroll
    for (int i = 0; i < 4; ++i) {
        const float v  = tile[tx][ty + 8*i];
        const short vh = f2bf(v);
        const short vl = f2bf(v - bf2f(vh));
        const int idx  = (n0 + ty + 8*i) * K + (k0 + tx);
        hi[idx] = vh;
        lo[idx] = vl;
    }
}

// ---------------------------------------------------------------------------
// QKV GEMM (R11). BM=128 BN=192 BK=32, 512 threads (8 waves 2Mx4N), per-wave
// output 64x48. LDS: 2 x 40KB buffers -> 2 blocks/CU. Counted-vmcnt schedule:
//   barrier A -> stage(t+1) -> vmcnt(5) -> barrier B (certify) -> ds_read
//   -> lgkmcnt(0) -> 36 MFMA.  No vmcnt(0) drain in the main loop.
// ---------------------------------------------------------------------------
#define QBUF_SH 20480          // shorts per LDS buffer (40KB)
#define OFF_AL  4096
#define OFF_BH  8192
#define OFF_BL  14336

__global__ __launch_bounds__(512, 4) void qkv_gemm8(
    const short* __restrict__ Xh, const short* __restrict__ Xl,
    const short* __restrict__ Bh, const short* __restrict__ Bl,
    const float* __restrict__ bias,
    short* __restrict__ Qo, short* __restrict__ Ko, short* __restrict__ Vt)
{
    __shared__ __attribute__((aligned(16))) short smem[2 * QBUF_SH];

    const int tid  = threadIdx.x;
    const int wave = tid >> 6, lane = tid & 63;
    const int q4 = lane >> 4, l16 = lane & 15;
    const int wr = wave >> 2, wc = wave & 3;
    const int csw = (q4 ^ ((l16 ^ (l16 >> 2)) & 3)) * 8;

    const int flat = blockIdx.x;
    const int sw = (flat & 7) * 64 + (flat >> 3);
    const int mt = sw & 31, nt = sw >> 5;
    const int m0 = mt * 128, n0 = nt * 192;

    // staging map: 2560 chunks = [Ah 512][Al 512][Bh 768][Bl 768], 5/thread
    const short* srcp[5];
#pragma unroll
    for (int j = 0; j < 5; ++j) {
        const int id = j * 512 + tid;
        int r; const short* mat; int row0;
        if (id < 512)       { r = id >> 2;          mat = Xh; row0 = m0; }
        else if (id < 1024) { r = (id - 512) >> 2;  mat = Xl; row0 = m0; }
        else if (id < 1792) { r = (id - 1024) >> 2; mat = Bh; row0 = n0; }
        else                { r = (id - 1792) >> 2; mat = Bl; row0 = n0; }
        const int cg = (id & 3) ^ ((r ^ (r >> 2)) & 3);
        srcp[j] = &mat[(size_t)(row0 + r) * D_MODEL + cg * 8];
    }

    auto stage = [&](int b) {
#pragma unroll
        for (int j = 0; j < 5; ++j) {
            gl16(srcp[j], smem + b * QBUF_SH + (j * 512 + tid) * 8);
            srcp[j] += 32;                  // advance one K-tile
        }
    };

    f32x4 acc[4][3];
#pragma unroll
    for (int i = 0; i < 4; ++i)
#pragma unroll
        for (int j = 0; j < 3; ++j) acc[i][j] = (f32x4){0.f, 0.f, 0.f, 0.f};

    stage(0);                               // tile 0 in flight

    for (int t = 0; t < 32; ++t) {
        const short* base = smem + (t & 1) * QBUF_SH;
        const short* Ah_s = base;
        const short* Al_s = base + OFF_AL;
        const short* Bh_s = base + OFF_BH;
        const short* Bl_s = base + OFF_BL;

        // barrier A: all waves finished READING the other buffer
        __builtin_amdgcn_s_barrier();
        if (t < 31) {
            stage((t + 1) & 1);             // write the just-released buffer
            // own stage(t) loads complete; stage(t+1)'s 5 remain in flight
            asm volatile("s_waitcnt vmcnt(5)" ::: "memory");
        } else {
            asm volatile("s_waitcnt vmcnt(0)" ::: "memory");
        }
        // barrier B: ALL waves' stage(t) complete -> buffer certified
        __builtin_amdgcn_s_barrier();
        __builtin_amdgcn_sched_barrier(0);

        // all 14 fragment ds_reads for this tile
        short8 bhf[3], blf[3], ahf[4], alf[4];
#pragma unroll
        for (int n = 0; n < 3; ++n) {
            const int rb = (wc * 48 + n * 16 + l16) * 32 + csw;
            bhf[n] = *(const short8*)(Bh_s + rb);
            blf[n] = *(const short8*)(Bl_s + rb);
        }
#pragma unroll
        for (int ti = 0; ti < 4; ++ti) {
            const int ra = (wr * 64 + ti * 16 + l16) * 32 + csw;
            ahf[ti] = *(const short8*)(Ah_s + ra);
            alf[ti] = *(const short8*)(Al_s + ra);
        }
        asm volatile("s_waitcnt lgkmcnt(0)" ::: "memory");
        __builtin_amdgcn_sched_barrier(0);
        __builtin_amdgcn_s_setprio(1);
#pragma unroll
        for (int ti = 0; ti < 4; ++ti)
#pragma unroll
            for (int n = 0; n < 3; ++n) {
                acc[ti][n] = __builtin_amdgcn_mfma_f32_16x16x32_bf16(ahf[ti], bhf[n], acc[ti][n], 0, 0, 0);
                acc[ti][n] = __builtin_amdgcn_mfma_f32_16x16x32_bf16(ahf[ti], blf[n], acc[ti][n], 0, 0, 0);
                acc[ti][n] = __builtin_amdgcn_mfma_f32_16x16x32_bf16(alf[ti], bhf[n], acc[ti][n], 0, 0, 0);
            }
        __builtin_amdgcn_s_setprio(0);
    }

    // epilogue: scatter Q (pre-scaled), K, Vt
    const float SCALE_Q = 0.125f * 1.4426950408889634f;
#pragma unroll
    for (int tj = 0; tj < 3; ++tj) {
        const int jj = wc * 48 + tj * 16 + l16;   // 0..191 within head
        const int n  = nt * 192 + jj;
        const float bv = bias[n];
#pragma unroll
        for (int ti = 0; ti < 4; ++ti) {
            const int mb = m0 + wr * 64 + ti * 16 + q4 * 4;
            const int b = mb >> 11;
            const int s = mb & 2047;
            const int bh_ = b * NHEAD + nt;
            if (jj >= 128) {                      // Vt: s is fast axis -> short4
                short4v v4;
#pragma unroll
                for (int r = 0; r < 4; ++r) v4[r] = f2bf(acc[ti][tj][r] + bv);
                *(short4v*)&Vt[(bh_ * HD + (jj - 128)) * SEQ + s] = v4;
            } else if (jj < 64) {
#pragma unroll
                for (int r = 0; r < 4; ++r)
                    Qo[(bh_ * SEQ + s + r) * HD + jj] = f2bf((acc[ti][tj][r] + bv) * SCALE_Q);
            } else {
#pragma unroll
                for (int r = 0; r < 4; ++r)
                    Ko[(bh_ * SEQ + s + r) * HD + (jj - 64)] = f2bf(acc[ti][tj][r] + bv);
            }
        }
    }
}

// ---------------------------------------------------------------------------
// Transposed-score flash attention (R8-measured 67.2us variant), KV-SPLIT x2.
// Grid (32 bh, 16 qb, 2 kvz); each block does 1024 keys (16 iters of 64),
// double-buffered K/V LDS, async reg-staging, ONE barrier per iter. Writes
// UNNORMALIZED O partial (f32, MFMA layout, coalesced) + per-row (m, l).
// ---------------------------------------------------------------------------
__global__ __launch_bounds__(256, 2) void attn_tscore(
    const short* __restrict__ Q, const short* __restrict__ K,
    const short* __restrict__ Vt,
    float* __restrict__ Opart, float2* __restrict__ Ml)
{
    __shared__ __attribute__((aligned(16))) char smem[36864];
    short (*Ks)[72] = (short(*)[72])smem;                 // [2*64 key][64 d + pad]
    short (*Vs)[72] = (short(*)[72])(smem + 18432);       // [2*64 d][64 key + pad]

    const int bh  = blockIdx.x;               // 0..31
    const int qb  = blockIdx.y;               // 0..15
    const int kvz = blockIdx.z;               // 0..1

    const short* Qp  = Q  + (size_t)bh * SEQ * HD;
    const short* Kp  = K  + (size_t)bh * SEQ * HD + (size_t)kvz * 1024 * HD;
    const short* Vtp = Vt + (size_t)bh * HD * SEQ + (size_t)kvz * 1024;

    const int tid  = threadIdx.x;
    const int wave = tid >> 6, lane = tid & 63;
    const int l5 = lane & 31, hf = lane >> 5;
    const int q0w = qb * 128 + wave * 32;

    short8 qf[4];
#pragma unroll
    for (int c = 0; c < 4; ++c)
        qf[c] = *(const short8*)&Qp[(q0w + l5) * HD + c * 16 + hf * 8];

    f32x16 oacc0 = (f32x16)(0.f), oacc1 = (f32x16)(0.f);
    float m = -1.0e30f, l = 0.f;

    // staging: 256 threads cover 64 rows x 64 cols (2x short8 each for K and V)
    const int sr = tid >> 2;          // 0..63
    const int sc = (tid & 3) * 16;    // 0,16,32,48

    short8 kr0 = *(const short8*)&Kp[sr * HD + sc];
    short8 kr1 = *(const short8*)&Kp[sr * HD + sc + 8];
    short8 vr0 = *(const short8*)&Vtp[sr * SEQ + sc];
    short8 vr1 = *(const short8*)&Vtp[sr * SEQ + sc + 8];
    *(short8*)&Ks[sr][sc]     = kr0;
    *(short8*)&Ks[sr][sc + 8] = kr1;
    *(short8*)&Vs[sr][sc]     = vr0;
    *(short8*)&Vs[sr][sc + 8] = vr1;
    __syncthreads();

    for (int kc = 0; kc < 16; ++kc) {
        const int buf = (kc & 1) << 6;

        // issue next tile's global loads (hidden under this tile's compute)
        if (kc < 15) {
            const int nkb = (kc + 1) << 6;
            kr0 = *(const short8*)&Kp[(nkb + sr) * HD + sc];
            kr1 = *(const short8*)&Kp[(nkb + sr) * HD + sc + 8];
            vr0 = *(const short8*)&Vtp[sr * SEQ + nkb + sc];
            vr1 = *(const short8*)&Vtp[sr * SEQ + nkb + sc + 8];
        }

        // ---- scores: two 32-key tiles ----
        f32x16 s0 = (f32x16)(0.f), s1 = (f32x16)(0.f);
#pragma unroll
        for (int c = 0; c < 4; ++c) {
            const short8 ka0 = *(const short8*)&Ks[buf + l5][c * 16 + hf * 8];
            const short8 ka1 = *(const short8*)&Ks[buf + 32 + l5][c * 16 + hf * 8];
            s0 = __builtin_amdgcn_mfma_f32_32x32x16_bf16(ka0, qf[c], s0, 0, 0, 0);
            s1 = __builtin_amdgcn_mfma_f32_32x32x16_bf16(ka1, qf[c], s1, 0, 0, 0);
        }

        // ---- row max over 32 scores/lane (+ cross-half) ----
        float t[8];
#pragma unroll
        for (int i = 0; i < 8; ++i)
            t[i] = fmaxf(fmaxf(s0[i], s0[i + 8]), fmaxf(s1[i], s1[i + 8]));
        float pmax = fmaxf(fmaxf(fmaxf(t[0], t[1]), fmaxf(t[2], t[3])),
                           fmaxf(fmaxf(t[4], t[5]), fmaxf(t[6], t[7])));
        pmax = fmaxf(pmax, __shfl_xor(pmax, 32, 64));

        // ---- defer-max (T13): rescale only when max grew past threshold ----
        if (!__all(pmax - m <= 8.0f)) {
            const float mnew  = fmaxf(m, pmax);
            const float alpha = exp2f(m - mnew);
#pragma unroll
            for (int i = 0; i < 16; ++i) { oacc0[i] *= alpha; oacc1[i] *= alpha; }
            l *= alpha;
            m = mnew;
        }

        // ---- P = exp2(S - m), row sum ----
        float p0[16], p1[16];
#pragma unroll
        for (int i = 0; i < 16; ++i) { p0[i] = exp2f(s0[i] - m); p1[i] = exp2f(s1[i] - m); }
        float sa = 0.f, sb = 0.f, sc_ = 0.f, sd = 0.f;
#pragma unroll
        for (int i = 0; i < 4; ++i) {
            sa += p0[i] + p0[i + 8];
            sb += p0[i + 4] + p0[i + 12];
            sc_ += p1[i] + p1[i + 8];
            sd += p1[i + 4] + p1[i + 12];
        }
        float rs = (sa + sb) + (sc_ + sd);
        rs += __shfl_xor(rs, 32, 64);
        l += rs;

        // ---- pack P -> 4 bf16 B-fragments (cvt_pk + permlane32_swap) ----
        unsigned u0 = cvtpk(p0[0],  p0[1]),  u1 = cvtpk(p0[2],  p0[3]);
        unsigned u2 = cvtpk(p0[4],  p0[5]),  u3 = cvtpk(p0[6],  p0[7]);
        unsigned u4 = cvtpk(p0[8],  p0[9]),  u5 = cvtpk(p0[10], p0[11]);
        unsigned u6 = cvtpk(p0[12], p0[13]), u7 = cvtpk(p0[14], p0[15]);
        unsigned w0 = cvtpk(p1[0],  p1[1]),  w1 = cvtpk(p1[2],  p1[3]);
        unsigned w2 = cvtpk(p1[4],  p1[5]),  w3 = cvtpk(p1[6],  p1[7]);
        unsigned w4 = cvtpk(p1[8],  p1[9]),  w5 = cvtpk(p1[10], p1[11]);
        unsigned w6 = cvtpk(p1[12], p1[13]), w7 = cvtpk(p1[14], p1[15]);
        PLSWAP(u0, u2); PLSWAP(u1, u3); PLSWAP(u4, u6); PLSWAP(u5, u7);
        PLSWAP(w0, w2); PLSWAP(w1, w3); PLSWAP(w4, w6); PLSWAP(w5, w7);
        int4v pb0 = (int4v){ (int)u0, (int)u1, (int)u2, (int)u3 };
        int4v pb1 = (int4v){ (int)u4, (int)u5, (int)u6, (int)u7 };
        int4v pb2 = (int4v){ (int)w0, (int)w1, (int)w2, (int)w3 };
        int4v pb3 = (int4v){ (int)w4, (int)w5, (int)w6, (int)w7 };
        const short8 pbf0 = __builtin_bit_cast(short8, pb0);
        const short8 pbf1 = __builtin_bit_cast(short8, pb1);
        const short8 pbf2 = __builtin_bit_cast(short8, pb2);
        const short8 pbf3 = __builtin_bit_cast(short8, pb3);

        // ---- PV: O += V[d][k-slice] . P ----
        {
            const short8 va0 = *(const short8*)&Vs[buf + l5][hf * 8];
            const short8 va1 = *(const short8*)&Vs[buf + l5][16 + hf * 8];
            const short8 va2 = *(const short8*)&Vs[buf + l5][32 + hf * 8];
            const short8 va3 = *(const short8*)&Vs[buf + l5][48 + hf * 8];
            oacc0 = __builtin_amdgcn_mfma_f32_32x32x16_bf16(va0, pbf0, oacc0, 0, 0, 0);
            oacc0 = __builtin_amdgcn_mfma_f32_32x32x16_bf16(va1, pbf1, oacc0, 0, 0, 0);
            oacc0 = __builtin_amdgcn_mfma_f32_32x32x16_bf16(va2, pbf2, oacc0, 0, 0, 0);
            oacc0 = __builtin_amdgcn_mfma_f32_32x32x16_bf16(va3, pbf3, oacc0, 0, 0, 0);
            const short8 vb0 = *(const short8*)&Vs[buf + 32 + l5][hf * 8];
            const short8 vb1 = *(const short8*)&Vs[buf + 32 + l5][16 + hf * 8];
            const short8 vb2 = *(const short8*)&Vs[buf + 32 + l5][32 + hf * 8];
            const short8 vb3 = *(const short8*)&Vs[buf + 32 + l5][48 + hf * 8];
            oacc1 = __builtin_amdgcn_mfma_f32_32x32x16_bf16(vb0, pbf0, oacc1, 0, 0, 0);
            oacc1 = __builtin_amdgcn_mfma_f32_32x32x16_bf16(vb1, pbf1, oacc1, 0, 0, 0);
            oacc1 = __builtin_amdgcn_mfma_f32_32x32x16_bf16(vb2, pbf2, oacc1, 0, 0, 0);
            oacc1 = __builtin_amdgcn_mfma_f32_32x32x16_bf16(vb3, pbf3, oacc1, 0, 0, 0);
        }

        // ---- write next tile into other buffer; one barrier per iter ----
        if (kc < 15) {
            const int wb = ((kc + 1) & 1) << 6;
            *(short8*)&Ks[wb + sr][sc]     = kr0;
            *(short8*)&Ks[wb + sr][sc + 8] = kr1;
            *(short8*)&Vs[wb + sr][sc]     = vr0;
            *(short8*)&Vs[wb + sr][sc + 8] = vr1;
        }
        __syncthreads();
    }

    // ---- partial epilogue: raw unnormalized O (MFMA layout) + (m,l) ----
    float* Op = Opart + ((((size_t)kvz * 32 + bh) * 16 + qb) * 4 + wave) * 2048;
#pragma unroll
    for (int r = 0; r < 4; ++r) {
        float4 v;
        v.x = oacc0[4*r]; v.y = oacc0[4*r+1]; v.z = oacc0[4*r+2]; v.w = oacc0[4*r+3];
        *(float4*)&Op[r * 256 + lane * 4] = v;
    }
#pragma unroll
    for (int r = 0; r < 4; ++r) {
        float4 v;
        v.x = oacc1[4*r]; v.y = oacc1[4*r+1]; v.z = oacc1[4*r+2]; v.w = oacc1[4*r+3];
        *(float4*)&Op[(4 + r) * 256 + lane * 4] = v;
    }
    if (hf == 0) {
        float2 mv; mv.x = m; mv.y = l;
        Ml[((size_t)kvz * 32 + bh) * 2048 + q0w + l5] = mv;
    }
}

// ---------------------------------------------------------------------------
// LSE-merge of the 2 KV partials -> split-bf16 ctx. One wave per 32-q group.
// ---------------------------------------------------------------------------
__global__ __launch_bounds__(256) void attn_merge(
    const float* __restrict__ Opart, const float2* __restrict__ Ml,
    short* __restrict__ Ch, short* __restrict__ Cl)
{
    __shared__ float epi[4][32][68];          // 34.8 KB
    const int tid = threadIdx.x, wave = tid >> 6, lane = tid & 63;
    const int l5 = lane & 31, hf = lane >> 5;
    const int task = blockIdx.x * 4 + wave;   // 0..2047
    const int bh = task >> 6;
    const int qb = (task >> 2) & 15;
    const int wq = task & 3;
    const int bi = bh >> 4, hi_ = bh & 15;
    const int q0w = qb * 128 + wq * 32;

    const float2 v0 = Ml[(size_t)bh * 2048 + q0w + l5];
    const float2 v1 = Ml[((size_t)32 + bh) * 2048 + q0w + l5];
    const float M  = fmaxf(v0.x, v1.x);
    const float w0 = exp2f(v0.x - M), w1 = exp2f(v1.x - M);
    const float inv = 1.0f / (v0.y * w0 + v1.y * w1);
    const float f0 = w0 * inv, f1 = w1 * inv;

    const float* Op0 = Opart + (((size_t)bh * 16 + qb) * 4 + wq) * 2048;
    const float* Op1 = Opart + ((((size_t)32 + bh) * 16 + qb) * 4 + wq) * 2048;
    float o[32];
#pragma unroll
    for (int r = 0; r < 8; ++r) {
        const float4 a = *(const float4*)&Op0[r * 256 + lane * 4];
        const float4 b = *(const float4*)&Op1[r * 256 + lane * 4];
        o[4*r]   = a.x * f0 + b.x * f1;
        o[4*r+1] = a.y * f0 + b.y * f1;
        o[4*r+2] = a.z * f0 + b.z * f1;
        o[4*r+3] = a.w * f0 + b.w * f1;
    }
#pragma unroll
    for (int r = 0; r < 16; ++r) {
        const int d = (r & 3) + 8 * (r >> 2) + 4 * hf;
        epi[wave][l5][d]      = o[r];
        epi[wave][l5][32 + d] = o[16 + r];
    }
    __builtin_amdgcn_s_waitcnt(0);
#pragma unroll
    for (int pass = 0; pass < 8; ++pass) {
        const int row = pass * 4 + (lane >> 4);
        const int col = (lane & 15) * 4;
        const float4 v = *(const float4*)&epi[wave][row][col];
        const float ov[4] = {v.x, v.y, v.z, v.w};
        short4v hh, ll;
#pragma unroll
        for (int i = 0; i < 4; ++i) {
            hh[i] = f2bf(ov[i]);
            ll[i] = f2bf(ov[i] - bf2f(hh[i]));
        }
        const size_t co = ((size_t)(bi * SEQ + q0w + row)) * D_MODEL + hi_ * HD + col;
        *(short4v*)&Ch[co] = hh;
        *(short4v*)&Cl[co] = ll;
    }
}

// ---------------------------------------------------------------------------
// Output GEMM v2 (R11): BM=128 BN=64 BK=32, 256 threads (4 waves 2Mx2N),
// per-wave 64x32. Counted-vmcnt + certify barrier, 2x24KB LDS, grid 512.
// ---------------------------------------------------------------------------
#define OBUF_SH 12288          // shorts per LDS buffer (24KB)
#define OO_AL   4096
#define OO_BH   8192
#define OO_BL   10240

__global__ __launch_bounds__(256, 4) void out_gemm2(
    const short* __restrict__ Ah, const short* __restrict__ Al,
    const short* __restrict__ Bh, const short* __restrict__ Bl,
    const float* __restrict__ bias, float* __restrict__ out)
{
    __shared__ __attribute__((aligned(16))) short smem[2 * OBUF_SH];

    const int tid  = threadIdx.x;
    const int wave = tid >> 6, lane = tid & 63;
    const int q4 = lane >> 4, l16 = lane & 15;
    const int wr = wave >> 1, wc = wave & 1;
    const int csw = (q4 ^ ((l16 ^ (l16 >> 2)) & 3)) * 8;

    const int flat = blockIdx.x;
    const int sw = (flat & 7) * 64 + (flat >> 3);
    const int mt = sw & 31, nt = sw >> 5;
    const int m0 = mt * 128, n0 = nt * 64;

    // staging map: 1536 chunks = [Ah 512][Al 512][Bh 256][Bl 256], 6/thread
    const short* srcp[6];
#pragma unroll
    for (int j = 0; j < 6; ++j) {
        const int id = j * 256 + tid;
        int r; const short* mat; int row0;
        if (id < 512)       { r = id >> 2;          mat = Ah; row0 = m0; }
        else if (id < 1024) { r = (id - 512) >> 2;  mat = Al; row0 = m0; }
        else if (id < 1280) { r = (id - 1024) >> 2; mat = Bh; row0 = n0; }
        else                { r = (id - 1280) >> 2; mat = Bl; row0 = n0; }
        const int cg = (id & 3) ^ ((r ^ (r >> 2)) & 3);
        srcp[j] = &mat[(size_t)(row0 + r) * D_MODEL + cg * 8];
    }

    auto stage = [&](int b) {
#pragma unroll
        for (int j = 0; j < 6; ++j) {
            gl16(srcp[j], smem + b * OBUF_SH + (j * 256 + tid) * 8);
            srcp[j] += 32;                  // advance one K-tile
        }
    };

    f32x4 acc[4][2];
#pragma unroll
    for (int i = 0; i < 4; ++i)
#pragma unroll
        for (int j = 0; j < 2; ++j) acc[i][j] = (f32x4){0.f, 0.f, 0.f, 0.f};

    stage(0);

    for (int t = 0; t < 32; ++t) {
        const short* base = smem + (t & 1) * OBUF_SH;
        const short* Ah_s = base;
        const short* Al_s = base + OO_AL;
        const short* Bh_s = base + OO_BH;
        const short* Bl_s = base + OO_BL;

        // barrier A: all waves finished READING the other buffer
        __builtin_amdgcn_s_barrier();
        if (t < 31) {
            stage((t + 1) & 1);
            asm volatile("s_waitcnt vmcnt(6)" ::: "memory");
        } else {
            asm volatile("s_waitcnt vmcnt(0)" ::: "memory");
        }
        // barrier B: ALL waves' stage(t) complete
        __builtin_amdgcn_s_barrier();
        __builtin_amdgcn_sched_barrier(0);

        short8 bhf[2], blf[2], ahf[4], alf[4];
#pragma unroll
        for (int n = 0; n < 2; ++n) {
            const int rb = (wc * 32 + n * 16 + l16) * 32 + csw;
            bhf[n] = *(const short8*)(Bh_s + rb);
            blf[n] = *(const short8*)(Bl_s + rb);
        }
#pragma unroll
        for (int ti = 0; ti < 4; ++ti) {
            const int ra = (wr * 64 + ti * 16 + l16) * 32 + csw;
            ahf[ti] = *(const short8*)(Ah_s + ra);
            alf[ti] = *(const short8*)(Al_s + ra);
        }
        asm volatile("s_waitcnt lgkmcnt(0)" ::: "memory");
        __builtin_amdgcn_sched_barrier(0);
        __builtin_amdgcn_s_setprio(1);
#pragma unroll
        for (int ti = 0; ti < 4; ++ti)
#pragma unroll
            for (int n = 0; n < 2; ++n) {
                acc[ti][n] = __builtin_amdgcn_mfma_f32_16x16x32_bf16(ahf[ti], bhf[n], acc[ti][n], 0, 0, 0);
                acc[ti][n] = __builtin_amdgcn_mfma_f32_16x16x32_bf16(ahf[ti], blf[n], acc[ti][n], 0, 0, 0);
                acc[ti][n] = __builtin_amdgcn_mfma_f32_16x16x32_bf16(alf[ti], bhf[n], acc[ti][n], 0, 0, 0);
            }
        __builtin_amdgcn_s_setprio(0);
    }

#pragma unroll
    for (int tj = 0; tj < 2; ++tj) {
        const int n = n0 + wc * 32 + tj * 16 + l16;
        const float bv = bias[n];
#pragma unroll
        for (int ti = 0; ti < 4; ++ti) {
            const int mb = m0 + wr * 64 + ti * 16 + q4 * 4;
#pragma unroll
            for (int r = 0; r < 4; ++r)
                out[(size_t)(mb + r) * D_MODEL + n] = acc[ti][tj][r] + bv;
        }
    }
}

// ---------------------------------------------------------------------------
// Workspace layout (peak 61MB, aliasing dead regions):
//   0- 2 Woh | 2- 4 Wol | 4-12 Qb (then Ch) | 12-20 Kb (then Cl) | 20-28 Vtb
//   28-60 Opart (before attn: 28-36 Xh, 36-44 Xl, 44-50 Wh, 50-56 Wl)
//   60-61 Ml
// ---------------------------------------------------------------------------
extern "C" void kernel_launch(void* const* d_in, const int* in_sizes, int n_in,
                              void* d_out, int out_size, void* d_ws, size_t ws_size,
                              hipStream_t stream)
{
    const float* x    = (const float*)d_in[0];
    const float* Wqkv = (const float*)d_in[1];
    const float* bqkv = (const float*)d_in[2];
    const float* Wout = (const float*)d_in[3];
    const float* bout = (const float*)d_in[4];
    float* out = (float*)d_out;

    char* ws = (char*)d_ws;
    short*  Woh   = (short*)(ws);             //  2 MB Wout^T hi
    short*  Wol   = (short*)(ws +  2*MB);     //  2 MB Wout^T lo
    short*  Qb    = (short*)(ws +  4*MB);     //  8 MB [32][2048][64] (pre-scaled)
    short*  Kb    = (short*)(ws + 12*MB);     //  8 MB
    short*  Vtb   = (short*)(ws + 20*MB);     //  8 MB [32][64][2048]
    float*  Opart = (float*)(ws + 28*MB);     // 32 MB [2][32][16][4][2048]
    float2* Ml    = (float2*)(ws + 60*MB);    //  1 MB [2][32][2048]
    short*  Ch    = (short*)(ws +  4*MB);     //  8 MB ctx hi  (aliases Qb)
    short*  Cl    = (short*)(ws + 12*MB);     //  8 MB ctx lo  (aliases Kb)
    short*  Xh    = (short*)(ws + 28*MB);     //  8 MB x hi    (aliases Opart)
    short*  Xl    = (short*)(ws + 36*MB);     //  8 MB x lo
    short*  Wh    = (short*)(ws + 44*MB);     //  6 MB Wqkv^T hi
    short*  Wl    = (short*)(ws + 50*MB);     //  6 MB Wqkv^T lo

    prep<<<6144, 256, 0, stream>>>(x, Wqkv, Wout, Xh, Xl, Wh, Wl, Woh, Wol);
    qkv_gemm8<<<dim3(512), 512, 0, stream>>>(Xh, Xl, Wh, Wl, bqkv, Qb, Kb, Vtb);
    attn_tscore<<<dim3(32, 16, 2), 256, 0, stream>>>(Qb, Kb, Vtb, Opart, Ml);
    attn_merge<<<512, 256, 0, stream>>>(Opart, Ml, Ch, Cl);
    out_gemm2<<<dim3(512), 256, 0, stream>>>(Ch, Cl, Woh, Wol, bout, out);
}